// Round 7
// baseline (1151.844 us; speedup 1.0000x reference)
//
#include <hip/hip_runtime.h>
#include <hip/hip_cooperative_groups.h>

namespace cg = cooperative_groups;

#define NN 200000
#define NE 3200000
static constexpr float EPSV = 1e-5f;

// ---------------- CSR build: 2-level bucket sort ----------------
__global__ void k_cnt(const int* __restrict__ ei, int* __restrict__ bktCnt){
  __shared__ int cnt[256];
  int t = threadIdx.x;
  cnt[t] = 0; __syncthreads();
  int tile = blockIdx.x*4096;
  #pragma unroll
  for (int k = 0; k < 16; ++k){
    int e = tile + k*256 + t;
    if (e < NE) atomicAdd(&cnt[ei[NE+e]>>10], 1);
  }
  __syncthreads();
  if (cnt[t]) atomicAdd(&bktCnt[t], cnt[t]);
}

__global__ void k_bktscan(const int* __restrict__ bktCnt, int* __restrict__ bktBase,
                          int* __restrict__ bktCur, int* __restrict__ off){
  __shared__ int s[256];
  int t = threadIdx.x;
  int v = bktCnt[t];
  s[t] = v; __syncthreads();
  for (int o = 1; o < 256; o <<= 1){
    int xv = (t >= o) ? s[t-o] : 0;
    __syncthreads(); s[t] += xv; __syncthreads();
  }
  int excl = s[t] - v;
  bktBase[t] = excl;
  bktCur[t]  = excl;
  if (t == 0){ bktBase[256] = NE; off[NN] = NE; }
}

__global__ void k_part1(const int* __restrict__ ei, int* __restrict__ bktCur,
                        int* __restrict__ pairs){
  __shared__ int cnt[256]; __shared__ int base[256]; __shared__ int rank[256];
  int t = threadIdx.x;   // 1024 threads
  if (t < 256) cnt[t] = 0;
  __syncthreads();
  int tile = blockIdx.x*16384;
  #pragma unroll
  for (int k = 0; k < 16; ++k){
    int e = tile + k*1024 + t;
    if (e < NE) atomicAdd(&cnt[ei[NE+e]>>10], 1);
  }
  __syncthreads();
  if (t < 256){
    base[t] = cnt[t] ? atomicAdd(&bktCur[t], cnt[t]) : 0;
    rank[t] = 0;
  }
  __syncthreads();
  #pragma unroll
  for (int k = 0; k < 16; ++k){
    int e = tile + k*1024 + t;
    if (e < NE){
      int d = ei[NE+e], s = ei[e];
      int b = d >> 10;
      int r = atomicAdd(&rank[b], 1);
      pairs[base[b] + r] = (s<<10) | (d & 1023);
    }
  }
}

__global__ void k_part2(const int* __restrict__ pairs, const int* __restrict__ bktBase,
                        int* __restrict__ off, int* __restrict__ srcs){
  __shared__ int hist[1024]; __shared__ int cur[1024];
  int b = blockIdx.x, t = threadIdx.x;
  int p0 = bktBase[b], p1 = bktBase[b+1];
  int cntB = p1 - p0;
  int dstBase = b << 10;
  int width = min(1024, NN - dstBase);
  hist[t] = 0; __syncthreads();
  for (int i = t; i < cntB; i += 1024) atomicAdd(&hist[pairs[p0+i] & 1023], 1);
  __syncthreads();
  int h0 = hist[t];
  for (int o = 1; o < 1024; o <<= 1){
    int xv = (t >= o) ? hist[t-o] : 0;
    __syncthreads(); hist[t] += xv; __syncthreads();
  }
  int excl = hist[t] - h0;
  if (t < width) off[dstBase + t] = p0 + excl;
  cur[t] = excl; __syncthreads();
  for (int i = t; i < cntB; i += 1024){
    int v = pairs[p0+i];
    int r = atomicAdd(&cur[v & 1023], 1);
    srcs[p0 + r] = v >> 10;
  }
}

// ---------------- Block 1 (N=200000, C=16), A in fp32 (lossless — gate flips!) ----------------
__global__ void k_prep1(const float* __restrict__ x, const float* __restrict__ pos,
                        const float* __restrict__ w, float* __restrict__ A,
                        float* __restrict__ xstats){
  int i = blockIdx.x*blockDim.x + threadIdx.x;
  float xf = 0.f;
  if (i < NN){
    xf = x[i];
    float px = pos[3*i], py = pos[3*i+1];
    #pragma unroll
    for (int c = 0; c < 16; ++c){
      A[i*16+c] = xf*w[c] + px*w[16+c] + py*w[32+c];
    }
  }
  __shared__ float sv[256], sq[256];
  int t = threadIdx.x;
  float v = (i < NN) ? xf : 0.f;
  sv[t] = v; sq[t] = v*v; __syncthreads();
  for (int o = 128; o > 0; o >>= 1){
    if (t < o){ sv[t]+=sv[t+o]; sq[t]+=sq[t+o]; } __syncthreads();
  }
  if (t == 0){ atomicAdd(&xstats[0], sv[0]); atomicAdd(&xstats[1], sq[0]); }
}

// CSR gather-max: 64 lanes per dst, 16 edges in flight, float4 channels.
__global__ void k_agg16w(const float4* __restrict__ A4, const int* __restrict__ srcs,
                         const int* __restrict__ off, const float* __restrict__ pos,
                         const float* __restrict__ wpos, const float* __restrict__ bias,
                         float4* __restrict__ H4){
  int t = threadIdx.x;
  int lane = t & 63;
  int d = blockIdx.x*4 + (t >> 6);
  int eidx = lane >> 2;
  int cg = lane & 3;
  int s0 = off[d], s1 = off[d+1];
  float NI = -__builtin_inff();
  float4 m = make_float4(NI, NI, NI, NI);
  for (int j = s0 + eidx; j < s1; j += 16){
    int s = srcs[j];
    float4 a = A4[s*4 + cg];
    m.x = fmaxf(m.x, a.x); m.y = fmaxf(m.y, a.y);
    m.z = fmaxf(m.z, a.z); m.w = fmaxf(m.w, a.w);
  }
  #pragma unroll
  for (int mask = 4; mask <= 32; mask <<= 1){
    m.x = fmaxf(m.x, __shfl_xor(m.x, mask, 64));
    m.y = fmaxf(m.y, __shfl_xor(m.y, mask, 64));
    m.z = fmaxf(m.z, __shfl_xor(m.z, mask, 64));
    m.w = fmaxf(m.w, __shfl_xor(m.w, mask, 64));
  }
  if (eidx == 0){
    float4 val = make_float4(0.f, 0.f, 0.f, 0.f);
    if (s1 > s0){
      float px = pos[3*d], py = pos[3*d+1];
      int c0 = cg*4;
      val.x = m.x + bias[c0+0] - (px*wpos[c0+0] + py*wpos[16+c0+0]);
      val.y = m.y + bias[c0+1] - (px*wpos[c0+1] + py*wpos[16+c0+1]);
      val.z = m.z + bias[c0+2] - (px*wpos[c0+2] + py*wpos[16+c0+2]);
      val.w = m.w + bias[c0+3] - (px*wpos[c0+3] + py*wpos[16+c0+3]);
    }
    H4[d*4 + cg] = val;
  }
}

__global__ void k_stats16(const float* __restrict__ H, float* __restrict__ st){
  int t = threadIdx.x;
  float s = 0.f, q = 0.f;
  for (int idx = blockIdx.x*256 + t; idx < NN*16; idx += gridDim.x*256){
    float v = H[idx]; s += v; q += v*v;
  }
  __shared__ float sv[256], sq[256];
  sv[t] = s; sq[t] = q; __syncthreads();
  for (int o = 128; o >= 16; o >>= 1){
    if (t < o){ sv[t]+=sv[t+o]; sq[t]+=sq[t+o]; } __syncthreads();
  }
  if (t < 16){ atomicAdd(&st[t], sv[t]); atomicAdd(&st[16+t], sq[t]); }
}

// A2 = relu(bn(Hraw)) @ c2w[0:16] + p . c2w[16:18]
__global__ void k_prep2(const float* __restrict__ Hraw, const float* __restrict__ st1,
                        const float* __restrict__ pos, const float* __restrict__ w,
                        float4* __restrict__ A4){
  int idx = blockIdx.x*blockDim.x + threadIdx.x;
  if (idx >= NN*4) return;
  int i = idx >> 2, cg = idx & 3;
  const float inv_n = 1.f/(float)NN;
  float acc0 = 0.f, acc1 = 0.f, acc2 = 0.f, acc3 = 0.f;
  #pragma unroll
  for (int k = 0; k < 16; ++k){
    float mk = st1[k]*inv_n;
    float vk = st1[16+k]*inv_n - mk*mk;
    float ik = rsqrtf(vk + EPSV);
    float h = fmaxf((Hraw[i*16+k]-mk)*ik, 0.f);
    acc0 += h*w[k*16 + cg*4 + 0];
    acc1 += h*w[k*16 + cg*4 + 1];
    acc2 += h*w[k*16 + cg*4 + 2];
    acc3 += h*w[k*16 + cg*4 + 3];
  }
  float px = pos[3*i], py = pos[3*i+1];
  int c0 = cg*4;
  acc0 += px*w[256+c0+0] + py*w[272+c0+0];
  acc1 += px*w[256+c0+1] + py*w[272+c0+1];
  acc2 += px*w[256+c0+2] + py*w[272+c0+2];
  acc3 += px*w[256+c0+3] + py*w[272+c0+3];
  A4[idx] = make_float4(acc0, acc1, acc2, acc3);
}

__global__ void k_comb_pool(const float* __restrict__ H, const float* __restrict__ x,
                            const float* __restrict__ pos, const float* __restrict__ lw,
                            const float* __restrict__ st2, const float* __restrict__ xstats,
                            float* __restrict__ mem){
  int idx = blockIdx.x*blockDim.x + threadIdx.x;
  if (idx >= NN*4) return;
  int i = idx >> 2, cg = idx & 3;
  const float inv_n = 1.f/(float)NN;
  float mx = xstats[0]*inv_n, vx = xstats[1]*inv_n - mx*mx;
  float xc = x[i] - mx;
  float px = pos[3*i], py = pos[3*i+1];
  int cx = (int)(px * 80.f / 240.f); cx = min(max(cx,0),79);
  int cy = (int)(py * 60.f / 180.f); cy = min(max(cy,0),59);
  float* mrow = &mem[(cy*80+cx)*16 + cg*4];
  #pragma unroll
  for (int k = 0; k < 4; ++k){
    int c = cg*4 + k;
    float m2 = st2[c]*inv_n, v2 = st2[16+c]*inv_n - m2*m2;
    float i2 = rsqrtf(v2 + EPSV);
    float a = lw[c];
    float sc = a * rsqrtf(a*a*vx + EPSV);
    float v = (H[i*16+c]-m2)*i2 + xc*sc;
    v = fmaxf(v, 0.f);
    atomicAdd(&mrow[k], v);
  }
}

// ---------------- Fused tail (blocks 2..4) — ONE cooperative kernel ----------------
struct TailP {
  const float *mem1;
  const float *p1w,*p1b,*p2w,*p2b,*p3w,*p3b;
  const float *c1w2,*c1b2,*c2w2,*c2b2,*lw2,*lb2;
  const float *c1w3,*c1b3,*c2w3,*c2b3,*lw3,*lb3;
  const float *c1w4,*c1b4,*c2w4,*c2b4,*lw4,*lb4;
  float *g1,*S2,*SK2,*H2,*g2f,*mem2,*g2p;
  float *S3,*SK3,*H3,*g3f,*mem3,*g3p;
  float *S4,*SK4,*H4;
  float *stB2sk,*stB2c1,*stB2c2,*stB3sk,*stB3c1,*stB3c2,*stB4sk,*stB4c1,*stB4c2;
  float *out;
};

__device__ __forceinline__ void d_poollin(const float* mem, const float* W, const float* b,
                                          float* G, int n, int C, int gid, int gs){
  for (int idx = gid; idx < n*C; idx += gs){
    int i = idx / C, c = idx % C;
    float acc = b[c];
    for (int k = 0; k < C; ++k) acc += mem[i*C+k]*W[k*C+c];
    G[idx] = (acc > 1.f) ? acc : 0.f;
  }
}

__device__ __forceinline__ void d_gmm(const float* X, const float* W, const float* bias,
                                      float* S, int n, int K, int C,
                                      float* st, const float* instats,
                                      float* sv, float* sq, int gid, int gs){
  const float inv_n = 1.f/(float)n;
  float ls = 0.f, lq = 0.f;
  for (int idx = gid; idx < n*C; idx += gs){
    int i = idx / C, c = idx % C;
    float acc = bias ? bias[c] : 0.f;
    for (int k = 0; k < K; ++k){
      float xk = X[i*K+k];
      if (instats){
        float mk = instats[k]*inv_n;
        float vk = instats[K+k]*inv_n - mk*mk;
        xk = fmaxf((xk-mk)*rsqrtf(vk+EPSV), 0.f);
      }
      acc += xk*W[k*C+c];
    }
    S[idx] = acc;
    ls += acc; lq += acc*acc;
  }
  if (st){
    int t = threadIdx.x;
    __syncthreads();
    sv[t] = ls; sq[t] = lq; __syncthreads();
    for (int o = 128; o >= C; o >>= 1){
      if (t < o){ sv[t]+=sv[t+o]; sq[t]+=sq[t+o]; } __syncthreads();
    }
    if (t < C){ atomicAdd(&st[t], sv[t]); atomicAdd(&st[C+t], sq[t]); }
    __syncthreads();
  }
}

__device__ __forceinline__ void d_gridagg(const float* S, const float* wpos, const float* bias,
                                          float* H, float* st, int n, int gw, int gh, int C,
                                          float sx, float sy,
                                          float* sv, float* sq, int gid, int gs){
  float ls = 0.f, lq = 0.f;
  for (int idx = gid; idx < n*C; idx += gs){
    int i = idx / C, c = idx % C;
    int x = i % gw, y = i / gw;
    float wx = wpos[c], wy = wpos[C+c];
    float m = -__builtin_inff();
    for (int oy = -1; oy <= 1; ++oy){
      int ny = y + oy; if (ny < 0 || ny >= gh) continue;
      for (int ox = -1; ox <= 1; ++ox){
        int nx = x + ox; if (nx < 0 || nx >= gw) continue;
        float v = S[(ny*gw+nx)*C + c] + (ox*sx)*wx + (oy*sy)*wy;
        m = fmaxf(m, v);
      }
    }
    float val = m + bias[c];
    H[idx] = val;
    ls += val; lq += val*val;
  }
  int t = threadIdx.x;
  __syncthreads();
  sv[t] = ls; sq[t] = lq; __syncthreads();
  for (int o = 128; o >= C; o >>= 1){
    if (t < o){ sv[t]+=sv[t+o]; sq[t]+=sq[t+o]; } __syncthreads();
  }
  if (t < C){ atomicAdd(&st[t], sv[t]); atomicAdd(&st[C+t], sq[t]); }
  __syncthreads();
}

__device__ __forceinline__ void d_gcombine(const float* H, const float* SK,
                                           const float* st2, const float* stsk,
                                           float* G, float* outf, int n, int C,
                                           int gid, int gs){
  const float inv_n = 1.f/(float)n;
  for (int idx = gid; idx < n*C; idx += gs){
    int c = idx % C;
    float m2 = st2[c]*inv_n, v2 = st2[C+c]*inv_n - m2*m2;
    float i2 = rsqrtf(v2 + EPSV);
    float ms = stsk[c]*inv_n, vs = stsk[C+c]*inv_n - ms*ms;
    float is_ = rsqrtf(vs + EPSV);
    float v = (H[idx]-m2)*i2 + (SK[idx]-ms)*is_;
    v = fmaxf(v, 0.f);
    if (G) G[idx] = v;
    outf[idx] = v;
  }
}

__device__ __forceinline__ void d_pool2x2(const float* G, float* mem,
                                          int gw, int gh, int C, int gid, int gs){
  int ow = gw >> 1;
  int n2 = ow*(gh>>1);
  for (int idx = gid; idx < n2*C; idx += gs){
    int i = idx / C, c = idx % C;
    int x = i % ow, y = i / ow;
    float a0 = G[((2*y)*gw + 2*x)*C + c];
    float a1 = G[((2*y)*gw + 2*x+1)*C + c];
    float a2 = G[((2*y+1)*gw + 2*x)*C + c];
    float a3 = G[((2*y+1)*gw + 2*x+1)*C + c];
    mem[idx] = ((a0 + a1) + a2) + a3;
  }
}

__global__ void __launch_bounds__(256) k_tail(TailP P){
  cg::grid_group gg = cg::this_grid();
  __shared__ float sv[256], sq[256];
  const int gid = blockIdx.x*256 + threadIdx.x;
  const int gs  = gridDim.x*256;

  d_poollin(P.mem1, P.p1w, P.p1b, P.g1, 4800, 16, gid, gs);
  gg.sync();
  // ---- block 2 (80x60, 16->32) ----
  d_gmm(P.g1, P.lw2, P.lb2, P.SK2, 4800, 16, 32, P.stB2sk, nullptr, sv, sq, gid, gs);
  d_gmm(P.g1, P.c1w2, nullptr, P.S2, 4800, 16, 32, nullptr, nullptr, sv, sq, gid, gs);
  gg.sync();
  d_gridagg(P.S2, P.c1w2+16*32, P.c1b2, P.H2, P.stB2c1, 4800, 80, 60, 32, 3.f, 3.f, sv, sq, gid, gs);
  gg.sync();
  d_gmm(P.H2, P.c2w2, nullptr, P.S2, 4800, 32, 32, nullptr, P.stB2c1, sv, sq, gid, gs);
  gg.sync();
  d_gridagg(P.S2, P.c2w2+32*32, P.c2b2, P.H2, P.stB2c2, 4800, 80, 60, 32, 3.f, 3.f, sv, sq, gid, gs);
  gg.sync();
  d_gcombine(P.H2, P.SK2, P.stB2c2, P.stB2sk, P.g2f, P.out, 4800, 32, gid, gs);
  gg.sync();
  d_pool2x2(P.g2f, P.mem2, 80, 60, 32, gid, gs);
  gg.sync();
  d_poollin(P.mem2, P.p2w, P.p2b, P.g2p, 1200, 32, gid, gs);
  gg.sync();
  // ---- block 3 (40x30, 32->64) ----
  d_gmm(P.g2p, P.lw3, P.lb3, P.SK3, 1200, 32, 64, P.stB3sk, nullptr, sv, sq, gid, gs);
  d_gmm(P.g2p, P.c1w3, nullptr, P.S3, 1200, 32, 64, nullptr, nullptr, sv, sq, gid, gs);
  gg.sync();
  d_gridagg(P.S3, P.c1w3+32*64, P.c1b3, P.H3, P.stB3c1, 1200, 40, 30, 64, 6.f, 6.f, sv, sq, gid, gs);
  gg.sync();
  d_gmm(P.H3, P.c2w3, nullptr, P.S3, 1200, 64, 64, nullptr, P.stB3c1, sv, sq, gid, gs);
  gg.sync();
  d_gridagg(P.S3, P.c2w3+64*64, P.c2b3, P.H3, P.stB3c2, 1200, 40, 30, 64, 6.f, 6.f, sv, sq, gid, gs);
  gg.sync();
  d_gcombine(P.H3, P.SK3, P.stB3c2, P.stB3sk, P.g3f, P.out+153600, 1200, 64, gid, gs);
  gg.sync();
  d_pool2x2(P.g3f, P.mem3, 40, 30, 64, gid, gs);
  gg.sync();
  d_poollin(P.mem3, P.p3w, P.p3b, P.g3p, 300, 64, gid, gs);
  gg.sync();
  // ---- block 4 (20x15, 64->128) ----
  d_gmm(P.g3p, P.lw4, P.lb4, P.SK4, 300, 64, 128, P.stB4sk, nullptr, sv, sq, gid, gs);
  d_gmm(P.g3p, P.c1w4, nullptr, P.S4, 300, 64, 128, nullptr, nullptr, sv, sq, gid, gs);
  gg.sync();
  d_gridagg(P.S4, P.c1w4+64*128, P.c1b4, P.H4, P.stB4c1, 300, 20, 15, 128, 12.f, 12.f, sv, sq, gid, gs);
  gg.sync();
  d_gmm(P.H4, P.c2w4, nullptr, P.S4, 300, 128, 128, nullptr, P.stB4c1, sv, sq, gid, gs);
  gg.sync();
  d_gridagg(P.S4, P.c2w4+128*128, P.c2b4, P.H4, P.stB4c2, 300, 20, 15, 128, 12.f, 12.f, sv, sq, gid, gs);
  gg.sync();
  d_gcombine(P.H4, P.SK4, P.stB4c2, P.stB4sk, nullptr, P.out+230400, 300, 128, gid, gs);
}

extern "C" void kernel_launch(void* const* d_in, const int* in_sizes, int n_in,
                              void* d_out, int out_size, void* d_ws, size_t ws_size,
                              hipStream_t stream){
  const float* x   = (const float*)d_in[0];
  const float* pos = (const float*)d_in[1];
  const int*   ei  = (const int*)d_in[2];
  const float* b1_c1w = (const float*)d_in[3];
  const float* b1_c1b = (const float*)d_in[4];
  const float* b1_c2w = (const float*)d_in[5];
  const float* b1_c2b = (const float*)d_in[6];
  const float* b1_lw  = (const float*)d_in[7];
  const float* b2_c1w = (const float*)d_in[9];
  const float* b2_c1b = (const float*)d_in[10];
  const float* b2_c2w = (const float*)d_in[11];
  const float* b2_c2b = (const float*)d_in[12];
  const float* b2_lw  = (const float*)d_in[13];
  const float* b2_lb  = (const float*)d_in[14];
  const float* b3_c1w = (const float*)d_in[15];
  const float* b3_c1b = (const float*)d_in[16];
  const float* b3_c2w = (const float*)d_in[17];
  const float* b3_c2b = (const float*)d_in[18];
  const float* b3_lw  = (const float*)d_in[19];
  const float* b3_lb  = (const float*)d_in[20];
  const float* b4_c1w = (const float*)d_in[21];
  const float* b4_c1b = (const float*)d_in[22];
  const float* b4_c2w = (const float*)d_in[23];
  const float* b4_c2b = (const float*)d_in[24];
  const float* b4_lw  = (const float*)d_in[25];
  const float* b4_lb  = (const float*)d_in[26];
  const float* p1w = (const float*)d_in[27];
  const float* p1b = (const float*)d_in[28];
  const float* p2w = (const float*)d_in[29];
  const float* p2b = (const float*)d_in[30];
  const float* p3w = (const float*)d_in[31];
  const float* p3b = (const float*)d_in[32];
  float* out = (float*)d_out;

  // ---- workspace carve ----
  float* A  = (float*)d_ws;          // NN*16 fp32 (12.8MB); pairs aliases (dead before A)
  int* pairs = (int*)A;              // NE ints — ALIAS
  float* H  = A + NN*16;             // NN*16
  float* ST = H + NN*16;             // 2048 floats
  float* xstats = ST;
  float* st1    = ST + 16;
  float* st2    = ST + 64;
  float* stB2sk = ST + 128;
  float* stB2c1 = ST + 192;
  float* stB2c2 = ST + 256;
  float* stB3sk = ST + 320;
  float* stB3c1 = ST + 448;
  float* stB3c2 = ST + 576;
  float* stB4sk = ST + 704;
  float* stB4c1 = ST + 960;
  float* stB4c2 = ST + 1216;
  float* SM   = ST + 2048;
  float* mem1 = SM;                  // 4800*16
  float* g1   = mem1 + 76800;
  float* b2S  = g1 + 76800;          // 4800*32
  float* b2SK = b2S + 153600;
  float* b2H  = b2SK + 153600;
  float* g2f  = b2H + 153600;
  float* mem2 = g2f + 153600;        // 1200*32
  float* g2p  = mem2 + 38400;
  float* b3S  = g2p + 38400;         // 1200*64
  float* b3SK = b3S + 76800;
  float* b3H  = b3SK + 76800;
  float* g3f  = b3H + 76800;
  float* mem3 = g3f + 76800;         // 300*64
  float* g3p  = mem3 + 19200;
  float* b4S  = g3p + 19200;         // 300*128
  float* b4SK = b4S + 38400;
  float* b4H  = b4SK + 38400;        // end floats
  int* off     = (int*)(b4H + 38400);  // NN+1
  int* srcs    = off + (NN+1);         // NE
  int* bktCnt  = srcs + NE;            // 256
  int* bktBase = bktCnt + 256;         // 257
  int* bktCur  = bktBase + 257;        // 256

  hipMemsetAsync(bktCnt, 0, 256*sizeof(int), stream);
  hipMemsetAsync(ST, 0, 2048*sizeof(float), stream);
  hipMemsetAsync(mem1, 0, 76800*sizeof(float), stream);

  const int B = 256;
  // CSR build (2-level bucket sort)
  k_cnt    <<<(NE+4095)/4096, 256, 0, stream>>>(ei, bktCnt);
  k_bktscan<<<1, 256, 0, stream>>>(bktCnt, bktBase, bktCur, off);
  k_part1  <<<(NE+16383)/16384, 1024, 0, stream>>>(ei, bktCur, pairs);
  k_part2  <<<196, 1024, 0, stream>>>(pairs, bktBase, off, srcs);

  // Block 1
  k_prep1   <<<(NN+B-1)/B, B, 0, stream>>>(x, pos, b1_c1w, A, xstats);
  k_agg16w  <<<NN/4, B, 0, stream>>>((const float4*)A, srcs, off, pos, b1_c1w+16, b1_c1b, (float4*)H);
  k_stats16 <<<256, B, 0, stream>>>(H, st1);
  k_prep2   <<<(NN*4+B-1)/B, B, 0, stream>>>(H, st1, pos, b1_c2w, (float4*)A);
  k_agg16w  <<<NN/4, B, 0, stream>>>((const float4*)A, srcs, off, pos, b1_c2w+256, b1_c2b, (float4*)H);
  k_stats16 <<<256, B, 0, stream>>>(H, st2);
  k_comb_pool<<<(NN*4+B-1)/B, B, 0, stream>>>(H, x, pos, b1_lw, st2, xstats, mem1);

  // Fused tail: blocks 2..4 in one cooperative kernel
  TailP P;
  P.mem1 = mem1;
  P.p1w = p1w; P.p1b = p1b; P.p2w = p2w; P.p2b = p2b; P.p3w = p3w; P.p3b = p3b;
  P.c1w2 = b2_c1w; P.c1b2 = b2_c1b; P.c2w2 = b2_c2w; P.c2b2 = b2_c2b; P.lw2 = b2_lw; P.lb2 = b2_lb;
  P.c1w3 = b3_c1w; P.c1b3 = b3_c1b; P.c2w3 = b3_c2w; P.c2b3 = b3_c2b; P.lw3 = b3_lw; P.lb3 = b3_lb;
  P.c1w4 = b4_c1w; P.c1b4 = b4_c1b; P.c2w4 = b4_c2w; P.c2b4 = b4_c2b; P.lw4 = b4_lw; P.lb4 = b4_lb;
  P.g1 = g1; P.S2 = b2S; P.SK2 = b2SK; P.H2 = b2H; P.g2f = g2f; P.mem2 = mem2; P.g2p = g2p;
  P.S3 = b3S; P.SK3 = b3SK; P.H3 = b3H; P.g3f = g3f; P.mem3 = mem3; P.g3p = g3p;
  P.S4 = b4S; P.SK4 = b4SK; P.H4 = b4H;
  P.stB2sk = stB2sk; P.stB2c1 = stB2c1; P.stB2c2 = stB2c2;
  P.stB3sk = stB3sk; P.stB3c1 = stB3c1; P.stB3c2 = stB3c2;
  P.stB4sk = stB4sk; P.stB4c1 = stB4c1; P.stB4c2 = stB4c2;
  P.out = out;
  void* kargs[] = { (void*)&P };
  hipLaunchCooperativeKernel((void*)k_tail, dim3(240), dim3(256), kargs, 0, stream);
}

// Round 8
// 740.724 us; speedup vs baseline: 1.5550x; 1.5550x over previous
//
#include <hip/hip_runtime.h>

#define NN 200000
#define NE 3200000
#define NWG 120
static constexpr float EPSV = 1e-5f;

// ---------------- CSR build: 2-level bucket sort ----------------
__global__ void k_cnt(const int* __restrict__ ei, int* __restrict__ bktCnt){
  __shared__ int cnt[256];
  int t = threadIdx.x;
  cnt[t] = 0; __syncthreads();
  int tile = blockIdx.x*4096;
  #pragma unroll
  for (int k = 0; k < 16; ++k){
    int e = tile + k*256 + t;
    if (e < NE) atomicAdd(&cnt[ei[NE+e]>>10], 1);
  }
  __syncthreads();
  if (cnt[t]) atomicAdd(&bktCnt[t], cnt[t]);
}

__global__ void k_bktscan(const int* __restrict__ bktCnt, int* __restrict__ bktBase,
                          int* __restrict__ bktCur, int* __restrict__ off){
  __shared__ int s[256];
  int t = threadIdx.x;
  int v = bktCnt[t];
  s[t] = v; __syncthreads();
  for (int o = 1; o < 256; o <<= 1){
    int xv = (t >= o) ? s[t-o] : 0;
    __syncthreads(); s[t] += xv; __syncthreads();
  }
  int excl = s[t] - v;
  bktBase[t] = excl;
  bktCur[t]  = excl;
  if (t == 0){ bktBase[256] = NE; off[NN] = NE; }
}

__global__ void k_part1(const int* __restrict__ ei, int* __restrict__ bktCur,
                        int* __restrict__ pairs){
  __shared__ int cnt[256]; __shared__ int base[256]; __shared__ int rank[256];
  int t = threadIdx.x;   // 1024 threads
  if (t < 256) cnt[t] = 0;
  __syncthreads();
  int tile = blockIdx.x*16384;
  #pragma unroll
  for (int k = 0; k < 16; ++k){
    int e = tile + k*1024 + t;
    if (e < NE) atomicAdd(&cnt[ei[NE+e]>>10], 1);
  }
  __syncthreads();
  if (t < 256){
    base[t] = cnt[t] ? atomicAdd(&bktCur[t], cnt[t]) : 0;
    rank[t] = 0;
  }
  __syncthreads();
  #pragma unroll
  for (int k = 0; k < 16; ++k){
    int e = tile + k*1024 + t;
    if (e < NE){
      int d = ei[NE+e], s = ei[e];
      int b = d >> 10;
      int r = atomicAdd(&rank[b], 1);
      pairs[base[b] + r] = (s<<10) | (d & 1023);
    }
  }
}

__global__ void k_part2(const int* __restrict__ pairs, const int* __restrict__ bktBase,
                        int* __restrict__ off, int* __restrict__ srcs){
  __shared__ int hist[1024]; __shared__ int cur[1024];
  int b = blockIdx.x, t = threadIdx.x;
  int p0 = bktBase[b], p1 = bktBase[b+1];
  int cntB = p1 - p0;
  int dstBase = b << 10;
  int width = min(1024, NN - dstBase);
  hist[t] = 0; __syncthreads();
  for (int i = t; i < cntB; i += 1024) atomicAdd(&hist[pairs[p0+i] & 1023], 1);
  __syncthreads();
  int h0 = hist[t];
  for (int o = 1; o < 1024; o <<= 1){
    int xv = (t >= o) ? hist[t-o] : 0;
    __syncthreads(); hist[t] += xv; __syncthreads();
  }
  int excl = hist[t] - h0;
  if (t < width) off[dstBase + t] = p0 + excl;
  cur[t] = excl; __syncthreads();
  for (int i = t; i < cntB; i += 1024){
    int v = pairs[p0+i];
    int r = atomicAdd(&cur[v & 1023], 1);
    srcs[p0 + r] = v >> 10;
  }
}

// ---------------- Block 1 (N=200000, C=16), A in fp32 (lossless) ----------------
__global__ void k_prep1(const float* __restrict__ x, const float* __restrict__ pos,
                        const float* __restrict__ w, float* __restrict__ A,
                        float* __restrict__ xstats){
  int i = blockIdx.x*blockDim.x + threadIdx.x;
  float xf = 0.f;
  if (i < NN){
    xf = x[i];
    float px = pos[3*i], py = pos[3*i+1];
    #pragma unroll
    for (int c = 0; c < 16; ++c){
      A[i*16+c] = xf*w[c] + px*w[16+c] + py*w[32+c];
    }
  }
  __shared__ float sv[256], sq[256];
  int t = threadIdx.x;
  float v = (i < NN) ? xf : 0.f;
  sv[t] = v; sq[t] = v*v; __syncthreads();
  for (int o = 128; o > 0; o >>= 1){
    if (t < o){ sv[t]+=sv[t+o]; sq[t]+=sq[t+o]; } __syncthreads();
  }
  if (t == 0){ atomicAdd(&xstats[0], sv[0]); atomicAdd(&xstats[1], sq[0]); }
}

__global__ void k_agg16w(const float4* __restrict__ A4, const int* __restrict__ srcs,
                         const int* __restrict__ off, const float* __restrict__ pos,
                         const float* __restrict__ wpos, const float* __restrict__ bias,
                         float4* __restrict__ H4){
  int t = threadIdx.x;
  int lane = t & 63;
  int d = blockIdx.x*4 + (t >> 6);
  int eidx = lane >> 2;
  int cg = lane & 3;
  int s0 = off[d], s1 = off[d+1];
  float NI = -__builtin_inff();
  float4 m = make_float4(NI, NI, NI, NI);
  for (int j = s0 + eidx; j < s1; j += 16){
    int s = srcs[j];
    float4 a = A4[s*4 + cg];
    m.x = fmaxf(m.x, a.x); m.y = fmaxf(m.y, a.y);
    m.z = fmaxf(m.z, a.z); m.w = fmaxf(m.w, a.w);
  }
  #pragma unroll
  for (int mask = 4; mask <= 32; mask <<= 1){
    m.x = fmaxf(m.x, __shfl_xor(m.x, mask, 64));
    m.y = fmaxf(m.y, __shfl_xor(m.y, mask, 64));
    m.z = fmaxf(m.z, __shfl_xor(m.z, mask, 64));
    m.w = fmaxf(m.w, __shfl_xor(m.w, mask, 64));
  }
  if (eidx == 0){
    float4 val = make_float4(0.f, 0.f, 0.f, 0.f);
    if (s1 > s0){
      float px = pos[3*d], py = pos[3*d+1];
      int c0 = cg*4;
      val.x = m.x + bias[c0+0] - (px*wpos[c0+0] + py*wpos[16+c0+0]);
      val.y = m.y + bias[c0+1] - (px*wpos[c0+1] + py*wpos[16+c0+1]);
      val.z = m.z + bias[c0+2] - (px*wpos[c0+2] + py*wpos[16+c0+2]);
      val.w = m.w + bias[c0+3] - (px*wpos[c0+3] + py*wpos[16+c0+3]);
    }
    H4[d*4 + cg] = val;
  }
}

__global__ void k_stats16(const float* __restrict__ H, float* __restrict__ st){
  int t = threadIdx.x;
  float s = 0.f, q = 0.f;
  for (int idx = blockIdx.x*256 + t; idx < NN*16; idx += gridDim.x*256){
    float v = H[idx]; s += v; q += v*v;
  }
  __shared__ float sv[256], sq[256];
  sv[t] = s; sq[t] = q; __syncthreads();
  for (int o = 128; o >= 16; o >>= 1){
    if (t < o){ sv[t]+=sv[t+o]; sq[t]+=sq[t+o]; } __syncthreads();
  }
  if (t < 16){ atomicAdd(&st[t], sv[t]); atomicAdd(&st[16+t], sq[t]); }
}

__global__ void k_prep2(const float* __restrict__ Hraw, const float* __restrict__ st1,
                        const float* __restrict__ pos, const float* __restrict__ w,
                        float4* __restrict__ A4){
  int idx = blockIdx.x*blockDim.x + threadIdx.x;
  if (idx >= NN*4) return;
  int i = idx >> 2, cg = idx & 3;
  const float inv_n = 1.f/(float)NN;
  float acc0 = 0.f, acc1 = 0.f, acc2 = 0.f, acc3 = 0.f;
  #pragma unroll
  for (int k = 0; k < 16; ++k){
    float mk = st1[k]*inv_n;
    float vk = st1[16+k]*inv_n - mk*mk;
    float ik = rsqrtf(vk + EPSV);
    float h = fmaxf((Hraw[i*16+k]-mk)*ik, 0.f);
    acc0 += h*w[k*16 + cg*4 + 0];
    acc1 += h*w[k*16 + cg*4 + 1];
    acc2 += h*w[k*16 + cg*4 + 2];
    acc3 += h*w[k*16 + cg*4 + 3];
  }
  float px = pos[3*i], py = pos[3*i+1];
  int c0 = cg*4;
  acc0 += px*w[256+c0+0] + py*w[272+c0+0];
  acc1 += px*w[256+c0+1] + py*w[272+c0+1];
  acc2 += px*w[256+c0+2] + py*w[272+c0+2];
  acc3 += px*w[256+c0+3] + py*w[272+c0+3];
  A4[idx] = make_float4(acc0, acc1, acc2, acc3);
}

__global__ void k_comb_pool(const float* __restrict__ H, const float* __restrict__ x,
                            const float* __restrict__ pos, const float* __restrict__ lw,
                            const float* __restrict__ st2, const float* __restrict__ xstats,
                            float* __restrict__ mem){
  int idx = blockIdx.x*blockDim.x + threadIdx.x;
  if (idx >= NN*4) return;
  int i = idx >> 2, cg = idx & 3;
  const float inv_n = 1.f/(float)NN;
  float mx = xstats[0]*inv_n, vx = xstats[1]*inv_n - mx*mx;
  float xc = x[i] - mx;
  float px = pos[3*i], py = pos[3*i+1];
  int cx = (int)(px * 80.f / 240.f); cx = min(max(cx,0),79);
  int cy = (int)(py * 60.f / 180.f); cy = min(max(cy,0),59);
  float* mrow = &mem[(cy*80+cx)*16 + cg*4];
  #pragma unroll
  for (int k = 0; k < 4; ++k){
    int c = cg*4 + k;
    float m2 = st2[c]*inv_n, v2 = st2[16+c]*inv_n - m2*m2;
    float i2 = rsqrtf(v2 + EPSV);
    float a = lw[c];
    float sc = a * rsqrtf(a*a*vx + EPSV);
    float v = (H[i*16+c]-m2)*i2 + xc*sc;
    v = fmaxf(v, 0.f);
    atomicAdd(&mrow[k], v);
  }
}

// ---------------- Fused tail with CUSTOM fast grid barrier ----------------
// bar layout (ints, zeroed each launch): [0..255] 8 slots stride 32; [256] master; [288] generation
__device__ __forceinline__ void gridbar(int* bar){
  __syncthreads();
  if (threadIdx.x == 0){
    int g = __hip_atomic_load(bar+288, __ATOMIC_RELAXED, __HIP_MEMORY_SCOPE_AGENT);
    __threadfence();   // release: publish this WG's writes
    int slot = blockIdx.x & 7;
    int a = __hip_atomic_fetch_add(bar + slot*32, 1, __ATOMIC_ACQ_REL, __HIP_MEMORY_SCOPE_AGENT);
    bool released = false;
    if (a == (NWG/8 - 1)){
      int m = __hip_atomic_fetch_add(bar + 256, 1, __ATOMIC_ACQ_REL, __HIP_MEMORY_SCOPE_AGENT);
      if (m == 7){
        #pragma unroll
        for (int s = 0; s < 8; ++s)
          __hip_atomic_store(bar + s*32, 0, __ATOMIC_RELAXED, __HIP_MEMORY_SCOPE_AGENT);
        __hip_atomic_store(bar + 256, 0, __ATOMIC_RELAXED, __HIP_MEMORY_SCOPE_AGENT);
        __hip_atomic_fetch_add(bar + 288, 1, __ATOMIC_RELEASE, __HIP_MEMORY_SCOPE_AGENT);
        released = true;
      }
    }
    if (!released){
      while (__hip_atomic_load(bar+288, __ATOMIC_RELAXED, __HIP_MEMORY_SCOPE_AGENT) == g)
        __builtin_amdgcn_s_sleep(1);
    }
    __threadfence();   // acquire: invalidate stale caches
  }
  __syncthreads();
}

struct TailP {
  const float *mem1;
  const float *p1w,*p1b,*p2w,*p2b,*p3w,*p3b;
  const float *c1w2,*c1b2,*c2w2,*c2b2,*lw2,*lb2;
  const float *c1w3,*c1b3,*c2w3,*c2b3,*lw3,*lb3;
  const float *c1w4,*c1b4,*c2w4,*c2b4,*lw4,*lb4;
  float *g1,*S2,*SK2,*H2,*g2p;
  float *S3,*SK3,*H3,*g3p;
  float *S4,*SK4,*H4;
  float *stB2sk,*stB2c1,*stB2c2,*stB3sk,*stB3c1,*stB3c2,*stB4sk,*stB4c1,*stB4c2;
  float *out;
  int *bar;
};

__device__ __forceinline__ void d_poollin(const float* mem, const float* W, const float* b,
                                          float* G, int n, int C, int gid, int gs){
  for (int idx = gid; idx < n*C; idx += gs){
    int i = idx / C, c = idx % C;
    float acc = b[c];
    for (int k = 0; k < C; ++k) acc += mem[i*C+k]*W[k*C+c];
    G[idx] = (acc > 1.f) ? acc : 0.f;
  }
}

// S = f(X)@W [+bias]; f = relu(bn) via LDS-precomputed (a,b) when instats given
__device__ __forceinline__ void d_gmm(const float* X, const float* W, const float* bias,
                                      float* S, int n, int K, int C,
                                      float* st, const float* instats,
                                      float* sv, float* sq, float* la, float* lb,
                                      int gid, int gs){
  const float inv_n = 1.f/(float)n;
  int t = threadIdx.x;
  if (instats){
    __syncthreads();
    if (t < K){
      float mk = instats[t]*inv_n;
      float vk = instats[K+t]*inv_n - mk*mk;
      float ik = rsqrtf(vk + EPSV);
      la[t] = ik; lb[t] = -mk*ik;
    }
    __syncthreads();
  }
  float ls = 0.f, lq = 0.f;
  for (int idx = gid; idx < n*C; idx += gs){
    int i = idx / C, c = idx % C;
    float acc = bias ? bias[c] : 0.f;
    for (int k = 0; k < K; ++k){
      float xk = X[i*K+k];
      if (instats) xk = fmaxf(fmaf(xk, la[k], lb[k]), 0.f);
      acc += xk*W[k*C+c];
    }
    S[idx] = acc;
    ls += acc; lq += acc*acc;
  }
  if (st){
    __syncthreads();
    sv[t] = ls; sq[t] = lq; __syncthreads();
    for (int o = 128; o >= C; o >>= 1){
      if (t < o){ sv[t]+=sv[t+o]; sq[t]+=sq[t+o]; } __syncthreads();
    }
    if (t < C){ atomicAdd(&st[t], sv[t]); atomicAdd(&st[C+t], sq[t]); }
    __syncthreads();
  }
}

__device__ __forceinline__ void d_gridagg(const float* S, const float* wpos, const float* bias,
                                          float* H, float* st, int n, int gw, int gh, int C,
                                          float sx, float sy,
                                          float* sv, float* sq, int gid, int gs){
  float ls = 0.f, lq = 0.f;
  for (int idx = gid; idx < n*C; idx += gs){
    int i = idx / C, c = idx % C;
    int x = i % gw, y = i / gw;
    float wx = wpos[c], wy = wpos[C+c];
    float m = -__builtin_inff();
    for (int oy = -1; oy <= 1; ++oy){
      int ny = y + oy; if (ny < 0 || ny >= gh) continue;
      for (int ox = -1; ox <= 1; ++ox){
        int nx = x + ox; if (nx < 0 || nx >= gw) continue;
        float v = S[(ny*gw+nx)*C + c] + (ox*sx)*wx + (oy*sy)*wy;
        m = fmaxf(m, v);
      }
    }
    float val = m + bias[c];
    H[idx] = val;
    ls += val; lq += val*val;
  }
  int t = threadIdx.x;
  __syncthreads();
  sv[t] = ls; sq[t] = lq; __syncthreads();
  for (int o = 128; o >= C; o >>= 1){
    if (t < o){ sv[t]+=sv[t+o]; sq[t]+=sq[t+o]; } __syncthreads();
  }
  if (t < C){ atomicAdd(&st[t], sv[t]); atomicAdd(&st[C+t], sq[t]); }
  __syncthreads();
}

// Fused: gcombine(H,SK)->out + 2x2 pool + poollin -> Gp. One WG owns PC pooled cells.
__device__ __forceinline__ void d_pool_stage(const float* H, const float* SK,
                                             const float* st2, const float* stsk,
                                             const float* W, const float* b,
                                             float* outf, float* Gp,
                                             int gw, int gh, int C, int PC,
                                             float* lmem, int nwg){
  int ow = gw >> 1;
  int ncell = ow*(gh>>1);
  int ntile = ncell / PC;
  int t = threadIdx.x;
  int cl = t / C;
  int c  = t % C;
  const float inv_n = 1.f/(float)(gw*gh);
  float m2 = st2[c]*inv_n, v2 = st2[C+c]*inv_n - m2*m2;
  float i2 = rsqrtf(v2 + EPSV);
  float ms = stsk[c]*inv_n, vs = stsk[C+c]*inv_n - ms*ms;
  float is_ = rsqrtf(vs + EPSV);
  for (int tile = blockIdx.x; tile < ntile; tile += nwg){
    int cell = tile*PC + cl;
    int px = cell % ow, py = cell / ow;
    float sum = 0.f;
    #pragma unroll
    for (int dy = 0; dy < 2; ++dy){
      #pragma unroll
      for (int dx = 0; dx < 2; ++dx){
        int gi = ((2*py+dy)*gw + (2*px+dx))*C + c;
        float v = (H[gi]-m2)*i2 + (SK[gi]-ms)*is_;
        v = fmaxf(v, 0.f);
        outf[gi] = v;
        sum += v;
      }
    }
    __syncthreads();
    lmem[cl*C + c] = sum;
    __syncthreads();
    float acc = b[c];
    for (int k = 0; k < C; ++k) acc += lmem[cl*C + k]*W[k*C+c];
    Gp[cell*C + c] = (acc > 1.f) ? acc : 0.f;
  }
}

__device__ __forceinline__ void d_gcombine(const float* H, const float* SK,
                                           const float* st2, const float* stsk,
                                           float* outf, int n, int C, int gid, int gs){
  const float inv_n = 1.f/(float)n;
  for (int idx = gid; idx < n*C; idx += gs){
    int c = idx % C;
    float m2 = st2[c]*inv_n, v2 = st2[C+c]*inv_n - m2*m2;
    float i2 = rsqrtf(v2 + EPSV);
    float ms = stsk[c]*inv_n, vs = stsk[C+c]*inv_n - ms*ms;
    float is_ = rsqrtf(vs + EPSV);
    float v = (H[idx]-m2)*i2 + (SK[idx]-ms)*is_;
    outf[idx] = fmaxf(v, 0.f);
  }
}

__global__ void __launch_bounds__(256) k_tail(TailP P){
  __shared__ float sv[256], sq[256], la[128], lb[128], lmem[256];
  const int gid = blockIdx.x*256 + threadIdx.x;
  const int gs  = NWG*256;
  int* bar = P.bar;

  d_poollin(P.mem1, P.p1w, P.p1b, P.g1, 4800, 16, gid, gs);
  gridbar(bar);
  // ---- block 2 (80x60, 16->32) ----
  d_gmm(P.g1, P.lw2, P.lb2, P.SK2, 4800, 16, 32, P.stB2sk, nullptr, sv, sq, la, lb, gid, gs);
  d_gmm(P.g1, P.c1w2, nullptr, P.S2, 4800, 16, 32, nullptr, nullptr, sv, sq, la, lb, gid, gs);
  gridbar(bar);
  d_gridagg(P.S2, P.c1w2+16*32, P.c1b2, P.H2, P.stB2c1, 4800, 80, 60, 32, 3.f, 3.f, sv, sq, gid, gs);
  gridbar(bar);
  d_gmm(P.H2, P.c2w2, nullptr, P.S2, 4800, 32, 32, nullptr, P.stB2c1, sv, sq, la, lb, gid, gs);
  gridbar(bar);
  d_gridagg(P.S2, P.c2w2+32*32, P.c2b2, P.H2, P.stB2c2, 4800, 80, 60, 32, 3.f, 3.f, sv, sq, gid, gs);
  gridbar(bar);
  d_pool_stage(P.H2, P.SK2, P.stB2c2, P.stB2sk, P.p2w, P.p2b, P.out, P.g2p, 80, 60, 32, 8, lmem, NWG);
  gridbar(bar);
  // ---- block 3 (40x30, 32->64) ----
  d_gmm(P.g2p, P.lw3, P.lb3, P.SK3, 1200, 32, 64, P.stB3sk, nullptr, sv, sq, la, lb, gid, gs);
  d_gmm(P.g2p, P.c1w3, nullptr, P.S3, 1200, 32, 64, nullptr, nullptr, sv, sq, la, lb, gid, gs);
  gridbar(bar);
  d_gridagg(P.S3, P.c1w3+32*64, P.c1b3, P.H3, P.stB3c1, 1200, 40, 30, 64, 6.f, 6.f, sv, sq, gid, gs);
  gridbar(bar);
  d_gmm(P.H3, P.c2w3, nullptr, P.S3, 1200, 64, 64, nullptr, P.stB3c1, sv, sq, la, lb, gid, gs);
  gridbar(bar);
  d_gridagg(P.S3, P.c2w3+64*64, P.c2b3, P.H3, P.stB3c2, 1200, 40, 30, 64, 6.f, 6.f, sv, sq, gid, gs);
  gridbar(bar);
  d_pool_stage(P.H3, P.SK3, P.stB3c2, P.stB3sk, P.p3w, P.p3b, P.out+153600, P.g3p, 40, 30, 64, 4, lmem, NWG);
  gridbar(bar);
  // ---- block 4 (20x15, 64->128) ----
  d_gmm(P.g3p, P.lw4, P.lb4, P.SK4, 300, 64, 128, P.stB4sk, nullptr, sv, sq, la, lb, gid, gs);
  d_gmm(P.g3p, P.c1w4, nullptr, P.S4, 300, 64, 128, nullptr, nullptr, sv, sq, la, lb, gid, gs);
  gridbar(bar);
  d_gridagg(P.S4, P.c1w4+64*128, P.c1b4, P.H4, P.stB4c1, 300, 20, 15, 128, 12.f, 12.f, sv, sq, gid, gs);
  gridbar(bar);
  d_gmm(P.H4, P.c2w4, nullptr, P.S4, 300, 128, 128, nullptr, P.stB4c1, sv, sq, la, lb, gid, gs);
  gridbar(bar);
  d_gridagg(P.S4, P.c2w4+128*128, P.c2b4, P.H4, P.stB4c2, 300, 20, 15, 128, 12.f, 12.f, sv, sq, gid, gs);
  gridbar(bar);
  d_gcombine(P.H4, P.SK4, P.stB4c2, P.stB4sk, P.out+230400, 300, 128, gid, gs);
}

extern "C" void kernel_launch(void* const* d_in, const int* in_sizes, int n_in,
                              void* d_out, int out_size, void* d_ws, size_t ws_size,
                              hipStream_t stream){
  const float* x   = (const float*)d_in[0];
  const float* pos = (const float*)d_in[1];
  const int*   ei  = (const int*)d_in[2];
  const float* b1_c1w = (const float*)d_in[3];
  const float* b1_c1b = (const float*)d_in[4];
  const float* b1_c2w = (const float*)d_in[5];
  const float* b1_c2b = (const float*)d_in[6];
  const float* b1_lw  = (const float*)d_in[7];
  const float* b2_c1w = (const float*)d_in[9];
  const float* b2_c1b = (const float*)d_in[10];
  const float* b2_c2w = (const float*)d_in[11];
  const float* b2_c2b = (const float*)d_in[12];
  const float* b2_lw  = (const float*)d_in[13];
  const float* b2_lb  = (const float*)d_in[14];
  const float* b3_c1w = (const float*)d_in[15];
  const float* b3_c1b = (const float*)d_in[16];
  const float* b3_c2w = (const float*)d_in[17];
  const float* b3_c2b = (const float*)d_in[18];
  const float* b3_lw  = (const float*)d_in[19];
  const float* b3_lb  = (const float*)d_in[20];
  const float* b4_c1w = (const float*)d_in[21];
  const float* b4_c1b = (const float*)d_in[22];
  const float* b4_c2w = (const float*)d_in[23];
  const float* b4_c2b = (const float*)d_in[24];
  const float* b4_lw  = (const float*)d_in[25];
  const float* b4_lb  = (const float*)d_in[26];
  const float* p1w = (const float*)d_in[27];
  const float* p1b = (const float*)d_in[28];
  const float* p2w = (const float*)d_in[29];
  const float* p2b = (const float*)d_in[30];
  const float* p3w = (const float*)d_in[31];
  const float* p3b = (const float*)d_in[32];
  float* out = (float*)d_out;

  // ---- workspace carve ----
  float* A  = (float*)d_ws;          // NN*16 fp32; pairs aliases (dead before A written)
  int* pairs = (int*)A;              // NE ints — ALIAS
  float* H  = A + NN*16;             // NN*16
  float* ST = H + NN*16;             // 2048 floats (zeroed each launch)
  float* xstats = ST;
  float* st1    = ST + 16;
  float* st2    = ST + 64;
  float* stB2sk = ST + 128;
  float* stB2c1 = ST + 192;
  float* stB2c2 = ST + 256;
  float* stB3sk = ST + 320;
  float* stB3c1 = ST + 448;
  float* stB3c2 = ST + 576;
  float* stB4sk = ST + 704;
  float* stB4c1 = ST + 960;
  float* stB4c2 = ST + 1216;          // ..1471
  int*   bar    = (int*)(ST + 1536);  // 320 ints, zeroed by ST memset
  float* SM   = ST + 2048;
  float* mem1 = SM;                  // 4800*16
  float* g1   = mem1 + 76800;
  float* b2S  = g1 + 76800;          // 4800*32
  float* b2SK = b2S + 153600;
  float* b2H  = b2SK + 153600;
  float* g2p  = b2H + 153600;        // 1200*32
  float* b3S  = g2p + 38400;         // 1200*64
  float* b3SK = b3S + 76800;
  float* b3H  = b3SK + 76800;
  float* g3p  = b3H + 76800;         // 300*64
  float* b4S  = g3p + 19200;         // 300*128
  float* b4SK = b4S + 38400;
  float* b4H  = b4SK + 38400;        // end floats
  int* off     = (int*)(b4H + 38400);  // NN+1
  int* srcs    = off + (NN+1);         // NE
  int* bktCnt  = srcs + NE;            // 256
  int* bktBase = bktCnt + 256;         // 257
  int* bktCur  = bktBase + 257;        // 256

  hipMemsetAsync(bktCnt, 0, 256*sizeof(int), stream);
  hipMemsetAsync(ST, 0, 2048*sizeof(float), stream);
  hipMemsetAsync(mem1, 0, 76800*sizeof(float), stream);

  const int B = 256;
  // CSR build (2-level bucket sort)
  k_cnt    <<<(NE+4095)/4096, 256, 0, stream>>>(ei, bktCnt);
  k_bktscan<<<1, 256, 0, stream>>>(bktCnt, bktBase, bktCur, off);
  k_part1  <<<(NE+16383)/16384, 1024, 0, stream>>>(ei, bktCur, pairs);
  k_part2  <<<196, 1024, 0, stream>>>(pairs, bktBase, off, srcs);

  // Block 1
  k_prep1   <<<(NN+B-1)/B, B, 0, stream>>>(x, pos, b1_c1w, A, xstats);
  k_agg16w  <<<NN/4, B, 0, stream>>>((const float4*)A, srcs, off, pos, b1_c1w+16, b1_c1b, (float4*)H);
  k_stats16 <<<256, B, 0, stream>>>(H, st1);
  k_prep2   <<<(NN*4+B-1)/B, B, 0, stream>>>(H, st1, pos, b1_c2w, (float4*)A);
  k_agg16w  <<<NN/4, B, 0, stream>>>((const float4*)A, srcs, off, pos, b1_c2w+256, b1_c2b, (float4*)H);
  k_stats16 <<<256, B, 0, stream>>>(H, st2);
  k_comb_pool<<<(NN*4+B-1)/B, B, 0, stream>>>(H, x, pos, b1_lw, st2, xstats, mem1);

  // Fused tail with custom grid barrier (regular launch; NWG=120 blocks co-resident trivially)
  TailP P;
  P.mem1 = mem1;
  P.p1w = p1w; P.p1b = p1b; P.p2w = p2w; P.p2b = p2b; P.p3w = p3w; P.p3b = p3b;
  P.c1w2 = b2_c1w; P.c1b2 = b2_c1b; P.c2w2 = b2_c2w; P.c2b2 = b2_c2b; P.lw2 = b2_lw; P.lb2 = b2_lb;
  P.c1w3 = b3_c1w; P.c1b3 = b3_c1b; P.c2w3 = b3_c2w; P.c2b3 = b3_c2b; P.lw3 = b3_lw; P.lb3 = b3_lb;
  P.c1w4 = b4_c1w; P.c1b4 = b4_c1b; P.c2w4 = b4_c2w; P.c2b4 = b4_c2b; P.lw4 = b4_lw; P.lb4 = b4_lb;
  P.g1 = g1; P.S2 = b2S; P.SK2 = b2SK; P.H2 = b2H; P.g2p = g2p;
  P.S3 = b3S; P.SK3 = b3SK; P.H3 = b3H; P.g3p = g3p;
  P.S4 = b4S; P.SK4 = b4SK; P.H4 = b4H;
  P.stB2sk = stB2sk; P.stB2c1 = stB2c1; P.stB2c2 = stB2c2;
  P.stB3sk = stB3sk; P.stB3c1 = stB3c1; P.stB3c2 = stB3c2;
  P.stB4sk = stB4sk; P.stB4c1 = stB4c1; P.stB4c2 = stB4c2;
  P.out = out; P.bar = bar;
  k_tail<<<NWG, 256, 0, stream>>>(P);
}

// Round 9
// 691.578 us; speedup vs baseline: 1.6655x; 1.0711x over previous
//
#include <hip/hip_runtime.h>

#define NN 200000
#define NE 3200000
#define NWG 120
static constexpr float EPSV = 1e-5f;

// ---------------- CSR build: 2-level bucket sort ----------------
__global__ void k_cnt(const int* __restrict__ ei, int* __restrict__ bktCnt){
  __shared__ int cnt[256];
  int t = threadIdx.x;
  cnt[t] = 0; __syncthreads();
  int tile = blockIdx.x*4096;
  #pragma unroll
  for (int k = 0; k < 16; ++k){
    int e = tile + k*256 + t;
    if (e < NE) atomicAdd(&cnt[ei[NE+e]>>10], 1);
  }
  __syncthreads();
  if (cnt[t]) atomicAdd(&bktCnt[t], cnt[t]);
}

__global__ void k_bktscan(const int* __restrict__ bktCnt, int* __restrict__ bktBase,
                          int* __restrict__ bktCur, int* __restrict__ off){
  __shared__ int s[256];
  int t = threadIdx.x;
  int v = bktCnt[t];
  s[t] = v; __syncthreads();
  for (int o = 1; o < 256; o <<= 1){
    int xv = (t >= o) ? s[t-o] : 0;
    __syncthreads(); s[t] += xv; __syncthreads();
  }
  int excl = s[t] - v;
  bktBase[t] = excl;
  bktCur[t]  = excl;
  if (t == 0){ bktBase[256] = NE; off[NN] = NE; }
}

__global__ void k_part1(const int* __restrict__ ei, int* __restrict__ bktCur,
                        int* __restrict__ pairs){
  __shared__ int cnt[256]; __shared__ int base[256]; __shared__ int rank[256];
  int t = threadIdx.x;   // 1024 threads
  if (t < 256) cnt[t] = 0;
  __syncthreads();
  int tile = blockIdx.x*16384;
  #pragma unroll
  for (int k = 0; k < 16; ++k){
    int e = tile + k*1024 + t;
    if (e < NE) atomicAdd(&cnt[ei[NE+e]>>10], 1);
  }
  __syncthreads();
  if (t < 256){
    base[t] = cnt[t] ? atomicAdd(&bktCur[t], cnt[t]) : 0;
    rank[t] = 0;
  }
  __syncthreads();
  #pragma unroll
  for (int k = 0; k < 16; ++k){
    int e = tile + k*1024 + t;
    if (e < NE){
      int d = ei[NE+e], s = ei[e];
      int b = d >> 10;
      int r = atomicAdd(&rank[b], 1);
      pairs[base[b] + r] = (s<<10) | (d & 1023);
    }
  }
}

__global__ void k_part2(const int* __restrict__ pairs, const int* __restrict__ bktBase,
                        int* __restrict__ off, int* __restrict__ srcs){
  __shared__ int hist[1024]; __shared__ int cur[1024];
  int b = blockIdx.x, t = threadIdx.x;
  int p0 = bktBase[b], p1 = bktBase[b+1];
  int cntB = p1 - p0;
  int dstBase = b << 10;
  int width = min(1024, NN - dstBase);
  hist[t] = 0; __syncthreads();
  for (int i = t; i < cntB; i += 1024) atomicAdd(&hist[pairs[p0+i] & 1023], 1);
  __syncthreads();
  int h0 = hist[t];
  for (int o = 1; o < 1024; o <<= 1){
    int xv = (t >= o) ? hist[t-o] : 0;
    __syncthreads(); hist[t] += xv; __syncthreads();
  }
  int excl = hist[t] - h0;
  if (t < width) off[dstBase + t] = p0 + excl;
  cur[t] = excl; __syncthreads();
  for (int i = t; i < cntB; i += 1024){
    int v = pairs[p0+i];
    int r = atomicAdd(&cur[v & 1023], 1);
    srcs[p0 + r] = v >> 10;
  }
}

// ---------------- Block 1 (N=200000, C=16) ----------------
// feat[i] = (x, px, py, 0): 16B/node — fits per-XCD L2 entirely (3.2MB)
__global__ void k_prep1(const float* __restrict__ x, const float* __restrict__ pos,
                        float4* __restrict__ feat, float* __restrict__ xstats){
  int i = blockIdx.x*blockDim.x + threadIdx.x;
  float xf = 0.f;
  if (i < NN){
    xf = x[i];
    feat[i] = make_float4(xf, pos[3*i], pos[3*i+1], 0.f);
  }
  __shared__ float sv[256], sq[256];
  int t = threadIdx.x;
  float v = (i < NN) ? xf : 0.f;
  sv[t] = v; sq[t] = v*v; __syncthreads();
  for (int o = 128; o > 0; o >>= 1){
    if (t < o){ sv[t]+=sv[t+o]; sq[t]+=sq[t+o]; } __syncthreads();
  }
  if (t == 0){ atomicAdd(&xstats[0], sv[0]); atomicAdd(&xstats[1], sq[0]); }
}

// Pass-1 gather-max: 16 lanes per dst, 1 edge/lane; 16B feat gather; weights in SGPRs.
__global__ void k_agg1(const float4* __restrict__ feat, const int* __restrict__ srcs,
                       const int* __restrict__ off, const float* __restrict__ pos,
                       const float* __restrict__ w48, const float* __restrict__ bias,
                       float4* __restrict__ H4){
  int t = threadIdx.x;
  int eidx = t & 15;
  int d = blockIdx.x*16 + (t >> 4);   // NN divisible by 16
  int s0 = off[d], s1 = off[d+1];
  float NI = -__builtin_inff();
  float m[16];
  #pragma unroll
  for (int c = 0; c < 16; ++c) m[c] = NI;
  for (int j = s0 + eidx; j < s1; j += 16){
    float4 f = feat[srcs[j]];
    #pragma unroll
    for (int c = 0; c < 16; ++c)
      m[c] = fmaxf(m[c], f.x*w48[c] + f.y*w48[16+c] + f.z*w48[32+c]);
  }
  #pragma unroll
  for (int mask = 1; mask < 16; mask <<= 1){
    #pragma unroll
    for (int c = 0; c < 16; ++c) m[c] = fmaxf(m[c], __shfl_xor(m[c], mask, 64));
  }
  if (eidx == 0){
    float o[16];
    if (s1 > s0){
      float px = pos[3*d], py = pos[3*d+1];
      #pragma unroll
      for (int c = 0; c < 16; ++c) o[c] = m[c] + bias[c] - (px*w48[16+c] + py*w48[32+c]);
    } else {
      #pragma unroll
      for (int c = 0; c < 16; ++c) o[c] = 0.f;
    }
    H4[d*4+0] = make_float4(o[0],o[1],o[2],o[3]);
    H4[d*4+1] = make_float4(o[4],o[5],o[6],o[7]);
    H4[d*4+2] = make_float4(o[8],o[9],o[10],o[11]);
    H4[d*4+3] = make_float4(o[12],o[13],o[14],o[15]);
  }
}

// Pass-2 gather-max (full-rank A2, fp32 64B rows): 64 lanes/dst, 16 edges in flight.
__global__ void k_agg16w(const float4* __restrict__ A4, const int* __restrict__ srcs,
                         const int* __restrict__ off, const float* __restrict__ pos,
                         const float* __restrict__ wpos, const float* __restrict__ bias,
                         float4* __restrict__ H4){
  int t = threadIdx.x;
  int lane = t & 63;
  int d = blockIdx.x*4 + (t >> 6);
  int eidx = lane >> 2;
  int cg = lane & 3;
  int s0 = off[d], s1 = off[d+1];
  float NI = -__builtin_inff();
  float4 m = make_float4(NI, NI, NI, NI);
  for (int j = s0 + eidx; j < s1; j += 16){
    int s = srcs[j];
    float4 a = A4[s*4 + cg];
    m.x = fmaxf(m.x, a.x); m.y = fmaxf(m.y, a.y);
    m.z = fmaxf(m.z, a.z); m.w = fmaxf(m.w, a.w);
  }
  #pragma unroll
  for (int mask = 4; mask <= 32; mask <<= 1){
    m.x = fmaxf(m.x, __shfl_xor(m.x, mask, 64));
    m.y = fmaxf(m.y, __shfl_xor(m.y, mask, 64));
    m.z = fmaxf(m.z, __shfl_xor(m.z, mask, 64));
    m.w = fmaxf(m.w, __shfl_xor(m.w, mask, 64));
  }
  if (eidx == 0){
    float4 val = make_float4(0.f, 0.f, 0.f, 0.f);
    if (s1 > s0){
      float px = pos[3*d], py = pos[3*d+1];
      int c0 = cg*4;
      val.x = m.x + bias[c0+0] - (px*wpos[c0+0] + py*wpos[16+c0+0]);
      val.y = m.y + bias[c0+1] - (px*wpos[c0+1] + py*wpos[16+c0+1]);
      val.z = m.z + bias[c0+2] - (px*wpos[c0+2] + py*wpos[16+c0+2]);
      val.w = m.w + bias[c0+3] - (px*wpos[c0+3] + py*wpos[16+c0+3]);
    }
    H4[d*4 + cg] = val;
  }
}

__global__ void k_stats16(const float* __restrict__ H, float* __restrict__ st){
  int t = threadIdx.x;
  float s = 0.f, q = 0.f;
  for (int idx = blockIdx.x*256 + t; idx < NN*16; idx += gridDim.x*256){
    float v = H[idx]; s += v; q += v*v;
  }
  __shared__ float sv[256], sq[256];
  sv[t] = s; sq[t] = q; __syncthreads();
  for (int o = 128; o >= 16; o >>= 1){
    if (t < o){ sv[t]+=sv[t+o]; sq[t]+=sq[t+o]; } __syncthreads();
  }
  if (t < 16){ atomicAdd(&st[t], sv[t]); atomicAdd(&st[16+t], sq[t]); }
}

__global__ void k_prep2(const float* __restrict__ Hraw, const float* __restrict__ st1,
                        const float* __restrict__ pos, const float* __restrict__ w,
                        float4* __restrict__ A4){
  int idx = blockIdx.x*blockDim.x + threadIdx.x;
  if (idx >= NN*4) return;
  int i = idx >> 2, cg = idx & 3;
  const float inv_n = 1.f/(float)NN;
  float acc0 = 0.f, acc1 = 0.f, acc2 = 0.f, acc3 = 0.f;
  #pragma unroll
  for (int k = 0; k < 16; ++k){
    float mk = st1[k]*inv_n;
    float vk = st1[16+k]*inv_n - mk*mk;
    float ik = rsqrtf(vk + EPSV);
    float h = fmaxf((Hraw[i*16+k]-mk)*ik, 0.f);
    acc0 += h*w[k*16 + cg*4 + 0];
    acc1 += h*w[k*16 + cg*4 + 1];
    acc2 += h*w[k*16 + cg*4 + 2];
    acc3 += h*w[k*16 + cg*4 + 3];
  }
  float px = pos[3*i], py = pos[3*i+1];
  int c0 = cg*4;
  acc0 += px*w[256+c0+0] + py*w[272+c0+0];
  acc1 += px*w[256+c0+1] + py*w[272+c0+1];
  acc2 += px*w[256+c0+2] + py*w[272+c0+2];
  acc3 += px*w[256+c0+3] + py*w[272+c0+3];
  A4[idx] = make_float4(acc0, acc1, acc2, acc3);
}

__global__ void k_comb_pool(const float* __restrict__ H, const float* __restrict__ x,
                            const float* __restrict__ pos, const float* __restrict__ lw,
                            const float* __restrict__ st2, const float* __restrict__ xstats,
                            float* __restrict__ mem){
  int idx = blockIdx.x*blockDim.x + threadIdx.x;
  if (idx >= NN*4) return;
  int i = idx >> 2, cg = idx & 3;
  const float inv_n = 1.f/(float)NN;
  float mx = xstats[0]*inv_n, vx = xstats[1]*inv_n - mx*mx;
  float xc = x[i] - mx;
  float px = pos[3*i], py = pos[3*i+1];
  int cx = (int)(px * 80.f / 240.f); cx = min(max(cx,0),79);
  int cy = (int)(py * 60.f / 180.f); cy = min(max(cy,0),59);
  float* mrow = &mem[(cy*80+cx)*16 + cg*4];
  #pragma unroll
  for (int k = 0; k < 4; ++k){
    int c = cg*4 + k;
    float m2 = st2[c]*inv_n, v2 = st2[16+c]*inv_n - m2*m2;
    float i2 = rsqrtf(v2 + EPSV);
    float a = lw[c];
    float sc = a * rsqrtf(a*a*vx + EPSV);
    float v = (H[i*16+c]-m2)*i2 + xc*sc;
    v = fmaxf(v, 0.f);
    atomicAdd(&mrow[k], v);
  }
}

// ---------------- Fused tail with write-through stores + cheap grid barrier ----------------
// All inter-stage tensor stores are agent-scope write-through (sc1): L2 stays clean,
// so the barrier's release wbl2 has nothing to write back and acquire inv is cheap.
__device__ __forceinline__ void stwt(float* p, float v){
  __hip_atomic_store(p, v, __ATOMIC_RELAXED, __HIP_MEMORY_SCOPE_AGENT);
}

__device__ __forceinline__ void gridbar(int* bar){
  __syncthreads();
  if (threadIdx.x == 0){
    __builtin_amdgcn_fence(__ATOMIC_RELEASE, "agent");   // wbl2: clean L2 -> fast
    int g = __hip_atomic_load(bar+288, __ATOMIC_RELAXED, __HIP_MEMORY_SCOPE_AGENT);
    int slot = blockIdx.x & 7;
    int a = __hip_atomic_fetch_add(bar + slot*32, 1, __ATOMIC_RELAXED, __HIP_MEMORY_SCOPE_AGENT);
    bool released = false;
    if (a == (NWG/8 - 1)){
      int m = __hip_atomic_fetch_add(bar + 256, 1, __ATOMIC_RELAXED, __HIP_MEMORY_SCOPE_AGENT);
      if (m == 7){
        #pragma unroll
        for (int s = 0; s < 8; ++s)
          __hip_atomic_store(bar + s*32, 0, __ATOMIC_RELAXED, __HIP_MEMORY_SCOPE_AGENT);
        __hip_atomic_store(bar + 256, 0, __ATOMIC_RELAXED, __HIP_MEMORY_SCOPE_AGENT);
        __hip_atomic_fetch_add(bar + 288, 1, __ATOMIC_RELEASE, __HIP_MEMORY_SCOPE_AGENT);
        released = true;
      }
    }
    if (!released){
      while (__hip_atomic_load(bar+288, __ATOMIC_RELAXED, __HIP_MEMORY_SCOPE_AGENT) == g)
        __builtin_amdgcn_s_sleep(1);
    }
    __builtin_amdgcn_fence(__ATOMIC_ACQUIRE, "agent");   // inv L1/L2 tags
  }
  __syncthreads();
}

struct TailP {
  const float *mem1;
  const float *p1w,*p1b,*p2w,*p2b,*p3w,*p3b;
  const float *c1w2,*c1b2,*c2w2,*c2b2,*lw2,*lb2;
  const float *c1w3,*c1b3,*c2w3,*c2b3,*lw3,*lb3;
  const float *c1w4,*c1b4,*c2w4,*c2b4,*lw4,*lb4;
  float *g1,*S2,*SK2,*H2,*g2p;
  float *S3,*SK3,*H3,*g3p;
  float *S4,*SK4,*H4;
  float *stB2sk,*stB2c1,*stB2c2,*stB3sk,*stB3c1,*stB3c2,*stB4sk,*stB4c1,*stB4c2;
  float *out;
  int *bar;
};

__device__ __forceinline__ void d_poollin(const float* mem, const float* W, const float* b,
                                          float* G, int n, int C, int gid, int gs){
  for (int idx = gid; idx < n*C; idx += gs){
    int i = idx / C, c = idx % C;
    float acc = b[c];
    for (int k = 0; k < C; ++k) acc += mem[i*C+k]*W[k*C+c];
    stwt(&G[idx], (acc > 1.f) ? acc : 0.f);
  }
}

__device__ __forceinline__ void d_gmm(const float* X, const float* W, const float* bias,
                                      float* S, int n, int K, int C,
                                      float* st, const float* instats,
                                      float* sv, float* sq, float* la, float* lb,
                                      int gid, int gs){
  const float inv_n = 1.f/(float)n;
  int t = threadIdx.x;
  if (instats){
    __syncthreads();
    if (t < K){
      float mk = instats[t]*inv_n;
      float vk = instats[K+t]*inv_n - mk*mk;
      float ik = rsqrtf(vk + EPSV);
      la[t] = ik; lb[t] = -mk*ik;
    }
    __syncthreads();
  }
  float ls = 0.f, lq = 0.f;
  for (int idx = gid; idx < n*C; idx += gs){
    int i = idx / C, c = idx % C;
    float acc = bias ? bias[c] : 0.f;
    for (int k = 0; k < K; ++k){
      float xk = X[i*K+k];
      if (instats) xk = fmaxf(fmaf(xk, la[k], lb[k]), 0.f);
      acc += xk*W[k*C+c];
    }
    stwt(&S[idx], acc);
    ls += acc; lq += acc*acc;
  }
  if (st){
    __syncthreads();
    sv[t] = ls; sq[t] = lq; __syncthreads();
    for (int o = 128; o >= C; o >>= 1){
      if (t < o){ sv[t]+=sv[t+o]; sq[t]+=sq[t+o]; } __syncthreads();
    }
    if (t < C){ atomicAdd(&st[t], sv[t]); atomicAdd(&st[C+t], sq[t]); }
    __syncthreads();
  }
}

__device__ __forceinline__ void d_gridagg(const float* S, const float* wpos, const float* bias,
                                          float* H, float* st, int n, int gw, int gh, int C,
                                          float sx, float sy,
                                          float* sv, float* sq, int gid, int gs){
  float ls = 0.f, lq = 0.f;
  for (int idx = gid; idx < n*C; idx += gs){
    int i = idx / C, c = idx % C;
    int x = i % gw, y = i / gw;
    float wx = wpos[c], wy = wpos[C+c];
    float m = -__builtin_inff();
    for (int oy = -1; oy <= 1; ++oy){
      int ny = y + oy; if (ny < 0 || ny >= gh) continue;
      for (int ox = -1; ox <= 1; ++ox){
        int nx = x + ox; if (nx < 0 || nx >= gw) continue;
        float v = S[(ny*gw+nx)*C + c] + (ox*sx)*wx + (oy*sy)*wy;
        m = fmaxf(m, v);
      }
    }
    float val = m + bias[c];
    stwt(&H[idx], val);
    ls += val; lq += val*val;
  }
  int t = threadIdx.x;
  __syncthreads();
  sv[t] = ls; sq[t] = lq; __syncthreads();
  for (int o = 128; o >= C; o >>= 1){
    if (t < o){ sv[t]+=sv[t+o]; sq[t]+=sq[t+o]; } __syncthreads();
  }
  if (t < C){ atomicAdd(&st[t], sv[t]); atomicAdd(&st[C+t], sq[t]); }
  __syncthreads();
}

// Fused: gcombine(H,SK)->out + 2x2 pool + poollin -> Gp. One WG owns PC pooled cells.
__device__ __forceinline__ void d_pool_stage(const float* H, const float* SK,
                                             const float* st2, const float* stsk,
                                             const float* W, const float* b,
                                             float* outf, float* Gp,
                                             int gw, int gh, int C, int PC,
                                             float* lmem, int nwg){
  int ow = gw >> 1;
  int ncell = ow*(gh>>1);
  int ntile = ncell / PC;
  int t = threadIdx.x;
  int cl = t / C;
  int c  = t % C;
  const float inv_n = 1.f/(float)(gw*gh);
  float m2 = st2[c]*inv_n, v2 = st2[C+c]*inv_n - m2*m2;
  float i2 = rsqrtf(v2 + EPSV);
  float ms = stsk[c]*inv_n, vs = stsk[C+c]*inv_n - ms*ms;
  float is_ = rsqrtf(vs + EPSV);
  for (int tile = blockIdx.x; tile < ntile; tile += nwg){
    int cell = tile*PC + cl;
    int px = cell % ow, py = cell / ow;
    float sum = 0.f;
    #pragma unroll
    for (int dy = 0; dy < 2; ++dy){
      #pragma unroll
      for (int dx = 0; dx < 2; ++dx){
        int gi = ((2*py+dy)*gw + (2*px+dx))*C + c;
        float v = (H[gi]-m2)*i2 + (SK[gi]-ms)*is_;
        v = fmaxf(v, 0.f);
        stwt(&outf[gi], v);
        sum += v;
      }
    }
    __syncthreads();
    lmem[cl*C + c] = sum;
    __syncthreads();
    float acc = b[c];
    for (int k = 0; k < C; ++k) acc += lmem[cl*C + k]*W[k*C+c];
    stwt(&Gp[cell*C + c], (acc > 1.f) ? acc : 0.f);
  }
}

__device__ __forceinline__ void d_gcombine(const float* H, const float* SK,
                                           const float* st2, const float* stsk,
                                           float* outf, int n, int C, int gid, int gs){
  const float inv_n = 1.f/(float)n;
  for (int idx = gid; idx < n*C; idx += gs){
    int c = idx % C;
    float m2 = st2[c]*inv_n, v2 = st2[C+c]*inv_n - m2*m2;
    float i2 = rsqrtf(v2 + EPSV);
    float ms = stsk[c]*inv_n, vs = stsk[C+c]*inv_n - ms*ms;
    float is_ = rsqrtf(vs + EPSV);
    float v = (H[idx]-m2)*i2 + (SK[idx]-ms)*is_;
    stwt(&outf[idx], fmaxf(v, 0.f));
  }
}

__global__ void __launch_bounds__(256) k_tail(TailP P){
  __shared__ float sv[256], sq[256], la[128], lb[128], lmem[256];
  const int gid = blockIdx.x*256 + threadIdx.x;
  const int gs  = NWG*256;
  int* bar = P.bar;

  d_poollin(P.mem1, P.p1w, P.p1b, P.g1, 4800, 16, gid, gs);
  gridbar(bar);
  // ---- block 2 (80x60, 16->32) ----
  d_gmm(P.g1, P.lw2, P.lb2, P.SK2, 4800, 16, 32, P.stB2sk, nullptr, sv, sq, la, lb, gid, gs);
  d_gmm(P.g1, P.c1w2, nullptr, P.S2, 4800, 16, 32, nullptr, nullptr, sv, sq, la, lb, gid, gs);
  gridbar(bar);
  d_gridagg(P.S2, P.c1w2+16*32, P.c1b2, P.H2, P.stB2c1, 4800, 80, 60, 32, 3.f, 3.f, sv, sq, gid, gs);
  gridbar(bar);
  d_gmm(P.H2, P.c2w2, nullptr, P.S2, 4800, 32, 32, nullptr, P.stB2c1, sv, sq, la, lb, gid, gs);
  gridbar(bar);
  d_gridagg(P.S2, P.c2w2+32*32, P.c2b2, P.H2, P.stB2c2, 4800, 80, 60, 32, 3.f, 3.f, sv, sq, gid, gs);
  gridbar(bar);
  d_pool_stage(P.H2, P.SK2, P.stB2c2, P.stB2sk, P.p2w, P.p2b, P.out, P.g2p, 80, 60, 32, 8, lmem, NWG);
  gridbar(bar);
  // ---- block 3 (40x30, 32->64) ----
  d_gmm(P.g2p, P.lw3, P.lb3, P.SK3, 1200, 32, 64, P.stB3sk, nullptr, sv, sq, la, lb, gid, gs);
  d_gmm(P.g2p, P.c1w3, nullptr, P.S3, 1200, 32, 64, nullptr, nullptr, sv, sq, la, lb, gid, gs);
  gridbar(bar);
  d_gridagg(P.S3, P.c1w3+32*64, P.c1b3, P.H3, P.stB3c1, 1200, 40, 30, 64, 6.f, 6.f, sv, sq, gid, gs);
  gridbar(bar);
  d_gmm(P.H3, P.c2w3, nullptr, P.S3, 1200, 64, 64, nullptr, P.stB3c1, sv, sq, la, lb, gid, gs);
  gridbar(bar);
  d_gridagg(P.S3, P.c2w3+64*64, P.c2b3, P.H3, P.stB3c2, 1200, 40, 30, 64, 6.f, 6.f, sv, sq, gid, gs);
  gridbar(bar);
  d_pool_stage(P.H3, P.SK3, P.stB3c2, P.stB3sk, P.p3w, P.p3b, P.out+153600, P.g3p, 40, 30, 64, 4, lmem, NWG);
  gridbar(bar);
  // ---- block 4 (20x15, 64->128) ----
  d_gmm(P.g3p, P.lw4, P.lb4, P.SK4, 300, 64, 128, P.stB4sk, nullptr, sv, sq, la, lb, gid, gs);
  d_gmm(P.g3p, P.c1w4, nullptr, P.S4, 300, 64, 128, nullptr, nullptr, sv, sq, la, lb, gid, gs);
  gridbar(bar);
  d_gridagg(P.S4, P.c1w4+64*128, P.c1b4, P.H4, P.stB4c1, 300, 20, 15, 128, 12.f, 12.f, sv, sq, gid, gs);
  gridbar(bar);
  d_gmm(P.H4, P.c2w4, nullptr, P.S4, 300, 128, 128, nullptr, P.stB4c1, sv, sq, la, lb, gid, gs);
  gridbar(bar);
  d_gridagg(P.S4, P.c2w4+128*128, P.c2b4, P.H4, P.stB4c2, 300, 20, 15, 128, 12.f, 12.f, sv, sq, gid, gs);
  gridbar(bar);
  d_gcombine(P.H4, P.SK4, P.stB4c2, P.stB4sk, P.out+230400, 300, 128, gid, gs);
}

extern "C" void kernel_launch(void* const* d_in, const int* in_sizes, int n_in,
                              void* d_out, int out_size, void* d_ws, size_t ws_size,
                              hipStream_t stream){
  const float* x   = (const float*)d_in[0];
  const float* pos = (const float*)d_in[1];
  const int*   ei  = (const int*)d_in[2];
  const float* b1_c1w = (const float*)d_in[3];
  const float* b1_c1b = (const float*)d_in[4];
  const float* b1_c2w = (const float*)d_in[5];
  const float* b1_c2b = (const float*)d_in[6];
  const float* b1_lw  = (const float*)d_in[7];
  const float* b2_c1w = (const float*)d_in[9];
  const float* b2_c1b = (const float*)d_in[10];
  const float* b2_c2w = (const float*)d_in[11];
  const float* b2_c2b = (const float*)d_in[12];
  const float* b2_lw  = (const float*)d_in[13];
  const float* b2_lb  = (const float*)d_in[14];
  const float* b3_c1w = (const float*)d_in[15];
  const float* b3_c1b = (const float*)d_in[16];
  const float* b3_c2w = (const float*)d_in[17];
  const float* b3_c2b = (const float*)d_in[18];
  const float* b3_lw  = (const float*)d_in[19];
  const float* b3_lb  = (const float*)d_in[20];
  const float* b4_c1w = (const float*)d_in[21];
  const float* b4_c1b = (const float*)d_in[22];
  const float* b4_c2w = (const float*)d_in[23];
  const float* b4_c2b = (const float*)d_in[24];
  const float* b4_lw  = (const float*)d_in[25];
  const float* b4_lb  = (const float*)d_in[26];
  const float* p1w = (const float*)d_in[27];
  const float* p1b = (const float*)d_in[28];
  const float* p2w = (const float*)d_in[29];
  const float* p2b = (const float*)d_in[30];
  const float* p3w = (const float*)d_in[31];
  const float* p3b = (const float*)d_in[32];
  float* out = (float*)d_out;

  // ---- workspace carve ----
  float4* feat = (float4*)d_ws;       // NN float4 (3.2MB)
  float* A  = (float*)(feat + NN);    // NN*16 fp32; pairs aliases (dead before A written)
  int* pairs = (int*)A;               // NE ints — ALIAS
  float* H  = A + NN*16;              // NN*16
  float* ST = H + NN*16;              // 2048 floats (zeroed each launch)
  float* xstats = ST;
  float* st1    = ST + 16;
  float* st2    = ST + 64;
  float* stB2sk = ST + 128;
  float* stB2c1 = ST + 192;
  float* stB2c2 = ST + 256;
  float* stB3sk = ST + 320;
  float* stB3c1 = ST + 448;
  float* stB3c2 = ST + 576;
  float* stB4sk = ST + 704;
  float* stB4c1 = ST + 960;
  float* stB4c2 = ST + 1216;          // ..1471
  int*   bar    = (int*)(ST + 1536);  // 320 ints, zeroed by ST memset
  float* SM   = ST + 2048;
  float* mem1 = SM;                  // 4800*16
  float* g1   = mem1 + 76800;
  float* b2S  = g1 + 76800;          // 4800*32
  float* b2SK = b2S + 153600;
  float* b2H  = b2SK + 153600;
  float* g2p  = b2H + 153600;        // 1200*32
  float* b3S  = g2p + 38400;         // 1200*64
  float* b3SK = b3S + 76800;
  float* b3H  = b3SK + 76800;
  float* g3p  = b3H + 76800;         // 300*64
  float* b4S  = g3p + 19200;         // 300*128
  float* b4SK = b4S + 38400;
  float* b4H  = b4SK + 38400;        // end floats
  int* off     = (int*)(b4H + 38400);  // NN+1
  int* srcs    = off + (NN+1);         // NE
  int* bktCnt  = srcs + NE;            // 256
  int* bktBase = bktCnt + 256;         // 257
  int* bktCur  = bktBase + 257;        // 256

  hipMemsetAsync(bktCnt, 0, 256*sizeof(int), stream);
  hipMemsetAsync(ST, 0, 2048*sizeof(float), stream);
  hipMemsetAsync(mem1, 0, 76800*sizeof(float), stream);

  const int B = 256;
  // CSR build (2-level bucket sort)
  k_cnt    <<<(NE+4095)/4096, 256, 0, stream>>>(ei, bktCnt);
  k_bktscan<<<1, 256, 0, stream>>>(bktCnt, bktBase, bktCur, off);
  k_part1  <<<(NE+16383)/16384, 1024, 0, stream>>>(ei, bktCur, pairs);
  k_part2  <<<196, 1024, 0, stream>>>(pairs, bktBase, off, srcs);

  // Block 1
  k_prep1   <<<(NN+B-1)/B, B, 0, stream>>>(x, pos, feat, xstats);
  k_agg1    <<<NN/16, B, 0, stream>>>(feat, srcs, off, pos, b1_c1w, b1_c1b, (float4*)H);
  k_stats16 <<<256, B, 0, stream>>>(H, st1);
  k_prep2   <<<(NN*4+B-1)/B, B, 0, stream>>>(H, st1, pos, b1_c2w, (float4*)A);
  k_agg16w  <<<NN/4, B, 0, stream>>>((const float4*)A, srcs, off, pos, b1_c2w+256, b1_c2b, (float4*)H);
  k_stats16 <<<256, B, 0, stream>>>(H, st2);
  k_comb_pool<<<(NN*4+B-1)/B, B, 0, stream>>>(H, x, pos, b1_lw, st2, xstats, mem1);

  // Fused tail with custom grid barrier (NWG=120 blocks, trivially co-resident)
  TailP P;
  P.mem1 = mem1;
  P.p1w = p1w; P.p1b = p1b; P.p2w = p2w; P.p2b = p2b; P.p3w = p3w; P.p3b = p3b;
  P.c1w2 = b2_c1w; P.c1b2 = b2_c1b; P.c2w2 = b2_c2w; P.c2b2 = b2_c2b; P.lw2 = b2_lw; P.lb2 = b2_lb;
  P.c1w3 = b3_c1w; P.c1b3 = b3_c1b; P.c2w3 = b3_c2w; P.c2b3 = b3_c2b; P.lw3 = b3_lw; P.lb3 = b3_lb;
  P.c1w4 = b4_c1w; P.c1b4 = b4_c1b; P.c2w4 = b4_c2w; P.c2b4 = b4_c2b; P.lw4 = b4_lw; P.lb4 = b4_lb;
  P.g1 = g1; P.S2 = b2S; P.SK2 = b2SK; P.H2 = b2H; P.g2p = g2p;
  P.S3 = b3S; P.SK3 = b3SK; P.H3 = b3H; P.g3p = g3p;
  P.S4 = b4S; P.SK4 = b4SK; P.H4 = b4H;
  P.stB2sk = stB2sk; P.stB2c1 = stB2c1; P.stB2c2 = stB2c2;
  P.stB3sk = stB3sk; P.stB3c1 = stB3c1; P.stB3c2 = stB3c2;
  P.stB4sk = stB4sk; P.stB4c1 = stB4c1; P.stB4c2 = stB4c2;
  P.out = out; P.bar = bar;
  k_tail<<<NWG, 256, 0, stream>>>(P);
}

// Round 10
// 687.018 us; speedup vs baseline: 1.6766x; 1.0066x over previous
//
#include <hip/hip_runtime.h>

#define NN 200000
#define NE 3200000
#define NWG 120
static constexpr float EPSV = 1e-5f;

// ---------------- CSR build: 2-level bucket sort ----------------
__global__ void k_cnt(const int* __restrict__ ei, int* __restrict__ bktCnt){
  __shared__ int cnt[256];
  int t = threadIdx.x;
  cnt[t] = 0; __syncthreads();
  int tile = blockIdx.x*4096;
  #pragma unroll
  for (int k = 0; k < 16; ++k){
    int e = tile + k*256 + t;
    if (e < NE) atomicAdd(&cnt[ei[NE+e]>>10], 1);
  }
  __syncthreads();
  if (cnt[t]) atomicAdd(&bktCnt[t], cnt[t]);
}

__global__ void k_bktscan(const int* __restrict__ bktCnt, int* __restrict__ bktBase,
                          int* __restrict__ bktCur, int* __restrict__ off){
  __shared__ int s[256];
  int t = threadIdx.x;
  int v = bktCnt[t];
  s[t] = v; __syncthreads();
  for (int o = 1; o < 256; o <<= 1){
    int xv = (t >= o) ? s[t-o] : 0;
    __syncthreads(); s[t] += xv; __syncthreads();
  }
  int excl = s[t] - v;
  bktBase[t] = excl;
  bktCur[t]  = excl;
  if (t == 0){ bktBase[256] = NE; off[NN] = NE; }
}

__global__ void k_part1(const int* __restrict__ ei, int* __restrict__ bktCur,
                        int* __restrict__ pairs){
  __shared__ int cnt[256]; __shared__ int base[256]; __shared__ int rank[256];
  int t = threadIdx.x;   // 1024 threads
  if (t < 256) cnt[t] = 0;
  __syncthreads();
  int tile = blockIdx.x*16384;
  #pragma unroll
  for (int k = 0; k < 16; ++k){
    int e = tile + k*1024 + t;
    if (e < NE) atomicAdd(&cnt[ei[NE+e]>>10], 1);
  }
  __syncthreads();
  if (t < 256){
    base[t] = cnt[t] ? atomicAdd(&bktCur[t], cnt[t]) : 0;
    rank[t] = 0;
  }
  __syncthreads();
  #pragma unroll
  for (int k = 0; k < 16; ++k){
    int e = tile + k*1024 + t;
    if (e < NE){
      int d = ei[NE+e], s = ei[e];
      int b = d >> 10;
      int r = atomicAdd(&rank[b], 1);
      pairs[base[b] + r] = (s<<10) | (d & 1023);
    }
  }
}

__global__ void k_part2(const int* __restrict__ pairs, const int* __restrict__ bktBase,
                        int* __restrict__ off, int* __restrict__ srcs){
  __shared__ int hist[1024]; __shared__ int cur[1024];
  int b = blockIdx.x, t = threadIdx.x;
  int p0 = bktBase[b], p1 = bktBase[b+1];
  int cntB = p1 - p0;
  int dstBase = b << 10;
  int width = min(1024, NN - dstBase);
  hist[t] = 0; __syncthreads();
  for (int i = t; i < cntB; i += 1024) atomicAdd(&hist[pairs[p0+i] & 1023], 1);
  __syncthreads();
  int h0 = hist[t];
  for (int o = 1; o < 1024; o <<= 1){
    int xv = (t >= o) ? hist[t-o] : 0;
    __syncthreads(); hist[t] += xv; __syncthreads();
  }
  int excl = hist[t] - h0;
  if (t < width) off[dstBase + t] = p0 + excl;
  cur[t] = excl; __syncthreads();
  for (int i = t; i < cntB; i += 1024){
    int v = pairs[p0+i];
    int r = atomicAdd(&cur[v & 1023], 1);
    srcs[p0 + r] = v >> 10;
  }
}

// ---------------- Block 1 (N=200000, C=16) ----------------
__global__ void k_prep1(const float* __restrict__ x, const float* __restrict__ pos,
                        float4* __restrict__ feat, float* __restrict__ xstats){
  int i = blockIdx.x*blockDim.x + threadIdx.x;
  float xf = 0.f;
  if (i < NN){
    xf = x[i];
    feat[i] = make_float4(xf, pos[3*i], pos[3*i+1], 0.f);
  }
  __shared__ float sv[256], sq[256];
  int t = threadIdx.x;
  float v = (i < NN) ? xf : 0.f;
  sv[t] = v; sq[t] = v*v; __syncthreads();
  for (int o = 128; o > 0; o >>= 1){
    if (t < o){ sv[t]+=sv[t+o]; sq[t]+=sq[t+o]; } __syncthreads();
  }
  if (t == 0){ atomicAdd(&xstats[0], sv[0]); atomicAdd(&xstats[1], sq[0]); }
}

__global__ void k_agg1(const float4* __restrict__ feat, const int* __restrict__ srcs,
                       const int* __restrict__ off, const float* __restrict__ pos,
                       const float* __restrict__ w48, const float* __restrict__ bias,
                       float4* __restrict__ H4){
  int t = threadIdx.x;
  int eidx = t & 15;
  int d = blockIdx.x*16 + (t >> 4);
  int s0 = off[d], s1 = off[d+1];
  float NI = -__builtin_inff();
  float m[16];
  #pragma unroll
  for (int c = 0; c < 16; ++c) m[c] = NI;
  for (int j = s0 + eidx; j < s1; j += 16){
    float4 f = feat[srcs[j]];
    #pragma unroll
    for (int c = 0; c < 16; ++c)
      m[c] = fmaxf(m[c], f.x*w48[c] + f.y*w48[16+c] + f.z*w48[32+c]);
  }
  #pragma unroll
  for (int mask = 1; mask < 16; mask <<= 1){
    #pragma unroll
    for (int c = 0; c < 16; ++c) m[c] = fmaxf(m[c], __shfl_xor(m[c], mask, 64));
  }
  if (eidx == 0){
    float o[16];
    if (s1 > s0){
      float px = pos[3*d], py = pos[3*d+1];
      #pragma unroll
      for (int c = 0; c < 16; ++c) o[c] = m[c] + bias[c] - (px*w48[16+c] + py*w48[32+c]);
    } else {
      #pragma unroll
      for (int c = 0; c < 16; ++c) o[c] = 0.f;
    }
    H4[d*4+0] = make_float4(o[0],o[1],o[2],o[3]);
    H4[d*4+1] = make_float4(o[4],o[5],o[6],o[7]);
    H4[d*4+2] = make_float4(o[8],o[9],o[10],o[11]);
    H4[d*4+3] = make_float4(o[12],o[13],o[14],o[15]);
  }
}

__global__ void k_agg16w(const float4* __restrict__ A4, const int* __restrict__ srcs,
                         const int* __restrict__ off, const float* __restrict__ pos,
                         const float* __restrict__ wpos, const float* __restrict__ bias,
                         float4* __restrict__ H4){
  int t = threadIdx.x;
  int lane = t & 63;
  int d = blockIdx.x*4 + (t >> 6);
  int eidx = lane >> 2;
  int cg = lane & 3;
  int s0 = off[d], s1 = off[d+1];
  float NI = -__builtin_inff();
  float4 m = make_float4(NI, NI, NI, NI);
  for (int j = s0 + eidx; j < s1; j += 16){
    int s = srcs[j];
    float4 a = A4[s*4 + cg];
    m.x = fmaxf(m.x, a.x); m.y = fmaxf(m.y, a.y);
    m.z = fmaxf(m.z, a.z); m.w = fmaxf(m.w, a.w);
  }
  #pragma unroll
  for (int mask = 4; mask <= 32; mask <<= 1){
    m.x = fmaxf(m.x, __shfl_xor(m.x, mask, 64));
    m.y = fmaxf(m.y, __shfl_xor(m.y, mask, 64));
    m.z = fmaxf(m.z, __shfl_xor(m.z, mask, 64));
    m.w = fmaxf(m.w, __shfl_xor(m.w, mask, 64));
  }
  if (eidx == 0){
    float4 val = make_float4(0.f, 0.f, 0.f, 0.f);
    if (s1 > s0){
      float px = pos[3*d], py = pos[3*d+1];
      int c0 = cg*4;
      val.x = m.x + bias[c0+0] - (px*wpos[c0+0] + py*wpos[16+c0+0]);
      val.y = m.y + bias[c0+1] - (px*wpos[c0+1] + py*wpos[16+c0+1]);
      val.z = m.z + bias[c0+2] - (px*wpos[c0+2] + py*wpos[16+c0+2]);
      val.w = m.w + bias[c0+3] - (px*wpos[c0+3] + py*wpos[16+c0+3]);
    }
    H4[d*4 + cg] = val;
  }
}

__global__ void k_stats16(const float* __restrict__ H, float* __restrict__ st){
  int t = threadIdx.x;
  float s = 0.f, q = 0.f;
  for (int idx = blockIdx.x*256 + t; idx < NN*16; idx += gridDim.x*256){
    float v = H[idx]; s += v; q += v*v;
  }
  __shared__ float sv[256], sq[256];
  sv[t] = s; sq[t] = q; __syncthreads();
  for (int o = 128; o >= 16; o >>= 1){
    if (t < o){ sv[t]+=sv[t+o]; sq[t]+=sq[t+o]; } __syncthreads();
  }
  if (t < 16){ atomicAdd(&st[t], sv[t]); atomicAdd(&st[16+t], sq[t]); }
}

__global__ void k_prep2(const float* __restrict__ Hraw, const float* __restrict__ st1,
                        const float* __restrict__ pos, const float* __restrict__ w,
                        float4* __restrict__ A4){
  int idx = blockIdx.x*blockDim.x + threadIdx.x;
  if (idx >= NN*4) return;
  int i = idx >> 2, cg = idx & 3;
  const float inv_n = 1.f/(float)NN;
  float acc0 = 0.f, acc1 = 0.f, acc2 = 0.f, acc3 = 0.f;
  #pragma unroll
  for (int k = 0; k < 16; ++k){
    float mk = st1[k]*inv_n;
    float vk = st1[16+k]*inv_n - mk*mk;
    float ik = rsqrtf(vk + EPSV);
    float h = fmaxf((Hraw[i*16+k]-mk)*ik, 0.f);
    acc0 += h*w[k*16 + cg*4 + 0];
    acc1 += h*w[k*16 + cg*4 + 1];
    acc2 += h*w[k*16 + cg*4 + 2];
    acc3 += h*w[k*16 + cg*4 + 3];
  }
  float px = pos[3*i], py = pos[3*i+1];
  int c0 = cg*4;
  acc0 += px*w[256+c0+0] + py*w[272+c0+0];
  acc1 += px*w[256+c0+1] + py*w[272+c0+1];
  acc2 += px*w[256+c0+2] + py*w[272+c0+2];
  acc3 += px*w[256+c0+3] + py*w[272+c0+3];
  A4[idx] = make_float4(acc0, acc1, acc2, acc3);
}

__global__ void k_comb_pool(const float* __restrict__ H, const float* __restrict__ x,
                            const float* __restrict__ pos, const float* __restrict__ lw,
                            const float* __restrict__ st2, const float* __restrict__ xstats,
                            float* __restrict__ mem){
  int idx = blockIdx.x*blockDim.x + threadIdx.x;
  if (idx >= NN*4) return;
  int i = idx >> 2, cg = idx & 3;
  const float inv_n = 1.f/(float)NN;
  float mx = xstats[0]*inv_n, vx = xstats[1]*inv_n - mx*mx;
  float xc = x[i] - mx;
  float px = pos[3*i], py = pos[3*i+1];
  int cx = (int)(px * 80.f / 240.f); cx = min(max(cx,0),79);
  int cy = (int)(py * 60.f / 180.f); cy = min(max(cy,0),59);
  float* mrow = &mem[(cy*80+cx)*16 + cg*4];
  #pragma unroll
  for (int k = 0; k < 4; ++k){
    int c = cg*4 + k;
    float m2 = st2[c]*inv_n, v2 = st2[16+c]*inv_n - m2*m2;
    float i2 = rsqrtf(v2 + EPSV);
    float a = lw[c];
    float sc = a * rsqrtf(a*a*vx + EPSV);
    float v = (H[i*16+c]-m2)*i2 + xc*sc;
    v = fmaxf(v, 0.f);
    atomicAdd(&mrow[k], v);
  }
}

// ---------------- Fused tail: fence-FREE coherence protocol ----------------
// Writes: agent-scope write-through (stwt) -> durable at coherent point once vmcnt=0.
// Reads of cross-barrier data: agent-scope relaxed loads (ldwt) -> always fetch
// coherent point, never stale L1/L2. => barriers need NO cache maintenance at all.
__device__ __forceinline__ void stwt(float* p, float v){
  __hip_atomic_store(p, v, __ATOMIC_RELAXED, __HIP_MEMORY_SCOPE_AGENT);
}
__device__ __forceinline__ float ldwt(const float* p){
  return __hip_atomic_load(p, __ATOMIC_RELAXED, __HIP_MEMORY_SCOPE_AGENT);
}

__device__ __forceinline__ void gridbar(int* bar){
  __syncthreads();
  if (threadIdx.x == 0){
    __atomic_signal_fence(__ATOMIC_SEQ_CST);
    __builtin_amdgcn_s_waitcnt(0);   // all my write-through stores durable at coherent point
    __atomic_signal_fence(__ATOMIC_SEQ_CST);
    int g = __hip_atomic_load(bar+288, __ATOMIC_RELAXED, __HIP_MEMORY_SCOPE_AGENT);
    int slot = blockIdx.x & 7;
    int a = __hip_atomic_fetch_add(bar + slot*32, 1, __ATOMIC_RELAXED, __HIP_MEMORY_SCOPE_AGENT);
    bool released = false;
    if (a == (NWG/8 - 1)){
      int m = __hip_atomic_fetch_add(bar + 256, 1, __ATOMIC_RELAXED, __HIP_MEMORY_SCOPE_AGENT);
      if (m == 7){
        #pragma unroll
        for (int s = 0; s < 8; ++s)
          __hip_atomic_store(bar + s*32, 0, __ATOMIC_RELAXED, __HIP_MEMORY_SCOPE_AGENT);
        __hip_atomic_store(bar + 256, 0, __ATOMIC_RELAXED, __HIP_MEMORY_SCOPE_AGENT);
        __atomic_signal_fence(__ATOMIC_SEQ_CST);
        __builtin_amdgcn_s_waitcnt(0);   // zeroing durable BEFORE generation bump
        __atomic_signal_fence(__ATOMIC_SEQ_CST);
        __hip_atomic_fetch_add(bar + 288, 1, __ATOMIC_RELAXED, __HIP_MEMORY_SCOPE_AGENT);
        released = true;
      }
    }
    if (!released){
      while (__hip_atomic_load(bar+288, __ATOMIC_RELAXED, __HIP_MEMORY_SCOPE_AGENT) == g)
        __builtin_amdgcn_s_sleep(2);
    }
  }
  __syncthreads();
}

struct TailP {
  const float *mem1;
  const float *p1w,*p1b,*p2w,*p2b,*p3w,*p3b;
  const float *c1w2,*c1b2,*c2w2,*c2b2,*lw2,*lb2;
  const float *c1w3,*c1b3,*c2w3,*c2b3,*lw3,*lb3;
  const float *c1w4,*c1b4,*c2w4,*c2b4,*lw4,*lb4;
  float *g1,*S2,*SK2,*H2,*g2p;
  float *S3,*SK3,*H3,*g3p;
  float *S4,*SK4,*H4;
  float *stB2sk,*stB2c1,*stB2c2,*stB3sk,*stB3c1,*stB3c2,*stB4sk,*stB4c1,*stB4c2;
  float *out;
  int *bar;
};

__device__ __forceinline__ void d_poollin(const float* mem, const float* W, const float* b,
                                          float* G, int n, int C, int gid, int gs){
  for (int idx = gid; idx < n*C; idx += gs){
    int i = idx / C, c = idx % C;
    float acc = b[c];
    for (int k = 0; k < C; ++k) acc += mem[i*C+k]*W[k*C+c];
    stwt(&G[idx], (acc > 1.f) ? acc : 0.f);
  }
}

__device__ __forceinline__ void d_gmm(const float* X, const float* W, const float* bias,
                                      float* S, int n, int K, int C,
                                      float* st, const float* instats,
                                      float* sv, float* sq, float* la, float* lb,
                                      int gid, int gs){
  const float inv_n = 1.f/(float)n;
  int t = threadIdx.x;
  if (instats){
    __syncthreads();
    if (t < K){
      float mk = ldwt(&instats[t])*inv_n;
      float vk = ldwt(&instats[K+t])*inv_n - mk*mk;
      float ik = rsqrtf(vk + EPSV);
      la[t] = ik; lb[t] = -mk*ik;
    }
    __syncthreads();
  }
  float ls = 0.f, lq = 0.f;
  for (int idx = gid; idx < n*C; idx += gs){
    int i = idx / C, c = idx % C;
    float acc = bias ? bias[c] : 0.f;
    for (int k = 0; k < K; ++k){
      float xk = ldwt(&X[i*K+k]);
      if (instats) xk = fmaxf(fmaf(xk, la[k], lb[k]), 0.f);
      acc += xk*W[k*C+c];
    }
    stwt(&S[idx], acc);
    ls += acc; lq += acc*acc;
  }
  if (st){
    __syncthreads();
    sv[t] = ls; sq[t] = lq; __syncthreads();
    for (int o = 128; o >= C; o >>= 1){
      if (t < o){ sv[t]+=sv[t+o]; sq[t]+=sq[t+o]; } __syncthreads();
    }
    if (t < C){ atomicAdd(&st[t], sv[t]); atomicAdd(&st[C+t], sq[t]); }
    __syncthreads();
  }
}

__device__ __forceinline__ void d_gridagg(const float* S, const float* wpos, const float* bias,
                                          float* H, float* st, int n, int gw, int gh, int C,
                                          float sx, float sy,
                                          float* sv, float* sq, int gid, int gs){
  float ls = 0.f, lq = 0.f;
  for (int idx = gid; idx < n*C; idx += gs){
    int i = idx / C, c = idx % C;
    int x = i % gw, y = i / gw;
    float wx = wpos[c], wy = wpos[C+c];
    float m = -__builtin_inff();
    for (int oy = -1; oy <= 1; ++oy){
      int ny = y + oy; if (ny < 0 || ny >= gh) continue;
      for (int ox = -1; ox <= 1; ++ox){
        int nx = x + ox; if (nx < 0 || nx >= gw) continue;
        float v = ldwt(&S[(ny*gw+nx)*C + c]) + (ox*sx)*wx + (oy*sy)*wy;
        m = fmaxf(m, v);
      }
    }
    float val = m + bias[c];
    stwt(&H[idx], val);
    ls += val; lq += val*val;
  }
  int t = threadIdx.x;
  __syncthreads();
  sv[t] = ls; sq[t] = lq; __syncthreads();
  for (int o = 128; o >= C; o >>= 1){
    if (t < o){ sv[t]+=sv[t+o]; sq[t]+=sq[t+o]; } __syncthreads();
  }
  if (t < C){ atomicAdd(&st[t], sv[t]); atomicAdd(&st[C+t], sq[t]); }
  __syncthreads();
}

// Fused: gcombine(H,SK)->out + 2x2 pool + poollin -> Gp. One WG owns PC pooled cells.
__device__ __forceinline__ void d_pool_stage(const float* H, const float* SK,
                                             const float* st2, const float* stsk,
                                             const float* W, const float* b,
                                             float* outf, float* Gp,
                                             int gw, int gh, int C, int PC,
                                             float* lmem, int nwg){
  int ow = gw >> 1;
  int ncell = ow*(gh>>1);
  int ntile = ncell / PC;
  int t = threadIdx.x;
  int cl = t / C;
  int c  = t % C;
  const float inv_n = 1.f/(float)(gw*gh);
  float m2 = ldwt(&st2[c])*inv_n, v2 = ldwt(&st2[C+c])*inv_n - m2*m2;
  float i2 = rsqrtf(v2 + EPSV);
  float ms = ldwt(&stsk[c])*inv_n, vs = ldwt(&stsk[C+c])*inv_n - ms*ms;
  float is_ = rsqrtf(vs + EPSV);
  for (int tile = blockIdx.x; tile < ntile; tile += nwg){
    int cell = tile*PC + cl;
    int px = cell % ow, py = cell / ow;
    float sum = 0.f;
    #pragma unroll
    for (int dy = 0; dy < 2; ++dy){
      #pragma unroll
      for (int dx = 0; dx < 2; ++dx){
        int gi = ((2*py+dy)*gw + (2*px+dx))*C + c;
        float v = (ldwt(&H[gi])-m2)*i2 + (ldwt(&SK[gi])-ms)*is_;
        v = fmaxf(v, 0.f);
        stwt(&outf[gi], v);
        sum += v;
      }
    }
    __syncthreads();
    lmem[cl*C + c] = sum;
    __syncthreads();
    float acc = b[c];
    for (int k = 0; k < C; ++k) acc += lmem[cl*C + k]*W[k*C+c];
    stwt(&Gp[cell*C + c], (acc > 1.f) ? acc : 0.f);
  }
}

__device__ __forceinline__ void d_gcombine(const float* H, const float* SK,
                                           const float* st2, const float* stsk,
                                           float* outf, int n, int C, int gid, int gs){
  const float inv_n = 1.f/(float)n;
  for (int idx = gid; idx < n*C; idx += gs){
    int c = idx % C;
    float m2 = ldwt(&st2[c])*inv_n, v2 = ldwt(&st2[C+c])*inv_n - m2*m2;
    float i2 = rsqrtf(v2 + EPSV);
    float ms = ldwt(&stsk[c])*inv_n, vs = ldwt(&stsk[C+c])*inv_n - ms*ms;
    float is_ = rsqrtf(vs + EPSV);
    float v = (ldwt(&H[idx])-m2)*i2 + (ldwt(&SK[idx])-ms)*is_;
    stwt(&outf[idx], fmaxf(v, 0.f));
  }
}

__global__ void __launch_bounds__(256) k_tail(TailP P){
  __shared__ float sv[256], sq[256], la[128], lb[128], lmem[256];
  const int gid = blockIdx.x*256 + threadIdx.x;
  const int gs  = NWG*256;
  int* bar = P.bar;

  d_poollin(P.mem1, P.p1w, P.p1b, P.g1, 4800, 16, gid, gs);
  gridbar(bar);
  // ---- block 2 (80x60, 16->32) ----
  d_gmm(P.g1, P.lw2, P.lb2, P.SK2, 4800, 16, 32, P.stB2sk, nullptr, sv, sq, la, lb, gid, gs);
  d_gmm(P.g1, P.c1w2, nullptr, P.S2, 4800, 16, 32, nullptr, nullptr, sv, sq, la, lb, gid, gs);
  gridbar(bar);
  d_gridagg(P.S2, P.c1w2+16*32, P.c1b2, P.H2, P.stB2c1, 4800, 80, 60, 32, 3.f, 3.f, sv, sq, gid, gs);
  gridbar(bar);
  d_gmm(P.H2, P.c2w2, nullptr, P.S2, 4800, 32, 32, nullptr, P.stB2c1, sv, sq, la, lb, gid, gs);
  gridbar(bar);
  d_gridagg(P.S2, P.c2w2+32*32, P.c2b2, P.H2, P.stB2c2, 4800, 80, 60, 32, 3.f, 3.f, sv, sq, gid, gs);
  gridbar(bar);
  d_pool_stage(P.H2, P.SK2, P.stB2c2, P.stB2sk, P.p2w, P.p2b, P.out, P.g2p, 80, 60, 32, 8, lmem, NWG);
  gridbar(bar);
  // ---- block 3 (40x30, 32->64) ----
  d_gmm(P.g2p, P.lw3, P.lb3, P.SK3, 1200, 32, 64, P.stB3sk, nullptr, sv, sq, la, lb, gid, gs);
  d_gmm(P.g2p, P.c1w3, nullptr, P.S3, 1200, 32, 64, nullptr, nullptr, sv, sq, la, lb, gid, gs);
  gridbar(bar);
  d_gridagg(P.S3, P.c1w3+32*64, P.c1b3, P.H3, P.stB3c1, 1200, 40, 30, 64, 6.f, 6.f, sv, sq, gid, gs);
  gridbar(bar);
  d_gmm(P.H3, P.c2w3, nullptr, P.S3, 1200, 64, 64, nullptr, P.stB3c1, sv, sq, la, lb, gid, gs);
  gridbar(bar);
  d_gridagg(P.S3, P.c2w3+64*64, P.c2b3, P.H3, P.stB3c2, 1200, 40, 30, 64, 6.f, 6.f, sv, sq, gid, gs);
  gridbar(bar);
  d_pool_stage(P.H3, P.SK3, P.stB3c2, P.stB3sk, P.p3w, P.p3b, P.out+153600, P.g3p, 40, 30, 64, 4, lmem, NWG);
  gridbar(bar);
  // ---- block 4 (20x15, 64->128) ----
  d_gmm(P.g3p, P.lw4, P.lb4, P.SK4, 300, 64, 128, P.stB4sk, nullptr, sv, sq, la, lb, gid, gs);
  d_gmm(P.g3p, P.c1w4, nullptr, P.S4, 300, 64, 128, nullptr, nullptr, sv, sq, la, lb, gid, gs);
  gridbar(bar);
  d_gridagg(P.S4, P.c1w4+64*128, P.c1b4, P.H4, P.stB4c1, 300, 20, 15, 128, 12.f, 12.f, sv, sq, gid, gs);
  gridbar(bar);
  d_gmm(P.H4, P.c2w4, nullptr, P.S4, 300, 128, 128, nullptr, P.stB4c1, sv, sq, la, lb, gid, gs);
  gridbar(bar);
  d_gridagg(P.S4, P.c2w4+128*128, P.c2b4, P.H4, P.stB4c2, 300, 20, 15, 128, 12.f, 12.f, sv, sq, gid, gs);
  gridbar(bar);
  d_gcombine(P.H4, P.SK4, P.stB4c2, P.stB4sk, P.out+230400, 300, 128, gid, gs);
}

extern "C" void kernel_launch(void* const* d_in, const int* in_sizes, int n_in,
                              void* d_out, int out_size, void* d_ws, size_t ws_size,
                              hipStream_t stream){
  const float* x   = (const float*)d_in[0];
  const float* pos = (const float*)d_in[1];
  const int*   ei  = (const int*)d_in[2];
  const float* b1_c1w = (const float*)d_in[3];
  const float* b1_c1b = (const float*)d_in[4];
  const float* b1_c2w = (const float*)d_in[5];
  const float* b1_c2b = (const float*)d_in[6];
  const float* b1_lw  = (const float*)d_in[7];
  const float* b2_c1w = (const float*)d_in[9];
  const float* b2_c1b = (const float*)d_in[10];
  const float* b2_c2w = (const float*)d_in[11];
  const float* b2_c2b = (const float*)d_in[12];
  const float* b2_lw  = (const float*)d_in[13];
  const float* b2_lb  = (const float*)d_in[14];
  const float* b3_c1w = (const float*)d_in[15];
  const float* b3_c1b = (const float*)d_in[16];
  const float* b3_c2w = (const float*)d_in[17];
  const float* b3_c2b = (const float*)d_in[18];
  const float* b3_lw  = (const float*)d_in[19];
  const float* b3_lb  = (const float*)d_in[20];
  const float* b4_c1w = (const float*)d_in[21];
  const float* b4_c1b = (const float*)d_in[22];
  const float* b4_c2w = (const float*)d_in[23];
  const float* b4_c2b = (const float*)d_in[24];
  const float* b4_lw  = (const float*)d_in[25];
  const float* b4_lb  = (const float*)d_in[26];
  const float* p1w = (const float*)d_in[27];
  const float* p1b = (const float*)d_in[28];
  const float* p2w = (const float*)d_in[29];
  const float* p2b = (const float*)d_in[30];
  const float* p3w = (const float*)d_in[31];
  const float* p3b = (const float*)d_in[32];
  float* out = (float*)d_out;

  // ---- workspace carve ----
  float4* feat = (float4*)d_ws;       // NN float4 (3.2MB)
  float* A  = (float*)(feat + NN);    // NN*16 fp32; pairs aliases (dead before A written)
  int* pairs = (int*)A;               // NE ints — ALIAS
  float* H  = A + NN*16;              // NN*16
  float* ST = H + NN*16;              // 2048 floats (zeroed each launch)
  float* xstats = ST;
  float* st1    = ST + 16;
  float* st2    = ST + 64;
  float* stB2sk = ST + 128;
  float* stB2c1 = ST + 192;
  float* stB2c2 = ST + 256;
  float* stB3sk = ST + 320;
  float* stB3c1 = ST + 448;
  float* stB3c2 = ST + 576;
  float* stB4sk = ST + 704;
  float* stB4c1 = ST + 960;
  float* stB4c2 = ST + 1216;          // ..1471
  int*   bar    = (int*)(ST + 1536);  // 320 ints, zeroed by ST memset
  float* SM   = ST + 2048;
  float* mem1 = SM;                  // 4800*16
  float* g1   = mem1 + 76800;
  float* b2S  = g1 + 76800;          // 4800*32
  float* b2SK = b2S + 153600;
  float* b2H  = b2SK + 153600;
  float* g2p  = b2H + 153600;        // 1200*32
  float* b3S  = g2p + 38400;         // 1200*64
  float* b3SK = b3S + 76800;
  float* b3H  = b3SK + 76800;
  float* g3p  = b3H + 76800;         // 300*64
  float* b4S  = g3p + 19200;         // 300*128
  float* b4SK = b4S + 38400;
  float* b4H  = b4SK + 38400;        // end floats
  int* off     = (int*)(b4H + 38400);  // NN+1
  int* srcs    = off + (NN+1);         // NE
  int* bktCnt  = srcs + NE;            // 256
  int* bktBase = bktCnt + 256;         // 257
  int* bktCur  = bktBase + 257;        // 256

  hipMemsetAsync(bktCnt, 0, 256*sizeof(int), stream);
  hipMemsetAsync(ST, 0, 2048*sizeof(float), stream);
  hipMemsetAsync(mem1, 0, 76800*sizeof(float), stream);

  const int B = 256;
  // CSR build (2-level bucket sort)
  k_cnt    <<<(NE+4095)/4096, 256, 0, stream>>>(ei, bktCnt);
  k_bktscan<<<1, 256, 0, stream>>>(bktCnt, bktBase, bktCur, off);
  k_part1  <<<(NE+16383)/16384, 1024, 0, stream>>>(ei, bktCur, pairs);
  k_part2  <<<196, 1024, 0, stream>>>(pairs, bktBase, off, srcs);

  // Block 1
  k_prep1   <<<(NN+B-1)/B, B, 0, stream>>>(x, pos, feat, xstats);
  k_agg1    <<<NN/16, B, 0, stream>>>(feat, srcs, off, pos, b1_c1w, b1_c1b, (float4*)H);
  k_stats16 <<<256, B, 0, stream>>>(H, st1);
  k_prep2   <<<(NN*4+B-1)/B, B, 0, stream>>>(H, st1, pos, b1_c2w, (float4*)A);
  k_agg16w  <<<NN/4, B, 0, stream>>>((const float4*)A, srcs, off, pos, b1_c2w+256, b1_c2b, (float4*)H);
  k_stats16 <<<256, B, 0, stream>>>(H, st2);
  k_comb_pool<<<(NN*4+B-1)/B, B, 0, stream>>>(H, x, pos, b1_lw, st2, xstats, mem1);

  // Fused tail with fence-free grid barrier (NWG=120 blocks, trivially co-resident)
  TailP P;
  P.mem1 = mem1;
  P.p1w = p1w; P.p1b = p1b; P.p2w = p2w; P.p2b = p2b; P.p3w = p3w; P.p3b = p3b;
  P.c1w2 = b2_c1w; P.c1b2 = b2_c1b; P.c2w2 = b2_c2w; P.c2b2 = b2_c2b; P.lw2 = b2_lw; P.lb2 = b2_lb;
  P.c1w3 = b3_c1w; P.c1b3 = b3_c1b; P.c2w3 = b3_c2w; P.c2b3 = b3_c2b; P.lw3 = b3_lw; P.lb3 = b3_lb;
  P.c1w4 = b4_c1w; P.c1b4 = b4_c1b; P.c2w4 = b4_c2w; P.c2b4 = b4_c2b; P.lw4 = b4_lw; P.lb4 = b4_lb;
  P.g1 = g1; P.S2 = b2S; P.SK2 = b2SK; P.H2 = b2H; P.g2p = g2p;
  P.S3 = b3S; P.SK3 = b3SK; P.H3 = b3H; P.g3p = g3p;
  P.S4 = b4S; P.SK4 = b4SK; P.H4 = b4H;
  P.stB2sk = stB2sk; P.stB2c1 = stB2c1; P.stB2c2 = stB2c2;
  P.stB3sk = stB3sk; P.stB3c1 = stB3c1; P.stB3c2 = stB3c2;
  P.stB4sk = stB4sk; P.stB4c1 = stB4c1; P.stB4c2 = stB4c2;
  P.out = out; P.bar = bar;
  k_tail<<<NWG, 256, 0, stream>>>(P);
}

// Round 11
// 686.350 us; speedup vs baseline: 1.6782x; 1.0010x over previous
//
#include <hip/hip_runtime.h>

#define NN 200000
#define NE 3200000
#define NWG 120
static constexpr float EPSV = 1e-5f;

// ---------------- CSR build: 2-level bucket sort ----------------
// k_cnt fused with prep1 (same 782x256 grid): edge-bucket histogram + feat build + x stats
__global__ void k_cnt_prep(const int* __restrict__ ei, int* __restrict__ bktCnt,
                           const float* __restrict__ x, const float* __restrict__ pos,
                           float4* __restrict__ feat, float* __restrict__ xstats){
  __shared__ int cnt[256];
  __shared__ float sv[256], sq[256];
  int t = threadIdx.x;
  cnt[t] = 0;
  int i = blockIdx.x*256 + t;
  float xf = 0.f;
  if (i < NN){
    xf = x[i];
    feat[i] = make_float4(xf, pos[3*i], pos[3*i+1], 0.f);
  }
  sv[t] = (i < NN) ? xf : 0.f;
  sq[t] = sv[t]*sv[t];
  __syncthreads();
  int tile = blockIdx.x*4096;
  #pragma unroll
  for (int k = 0; k < 16; ++k){
    int e = tile + k*256 + t;
    if (e < NE) atomicAdd(&cnt[ei[NE+e]>>10], 1);
  }
  for (int o = 128; o > 0; o >>= 1){
    __syncthreads();
    if (t < o){ sv[t]+=sv[t+o]; sq[t]+=sq[t+o]; }
  }
  __syncthreads();
  if (t == 0){ atomicAdd(&xstats[0], sv[0]); atomicAdd(&xstats[1], sq[0]); }
  if (cnt[t]) atomicAdd(&bktCnt[t], cnt[t]);
}

__global__ void k_bktscan(const int* __restrict__ bktCnt, int* __restrict__ bktBase,
                          int* __restrict__ bktCur, int* __restrict__ off){
  __shared__ int s[256];
  int t = threadIdx.x;
  int v = bktCnt[t];
  s[t] = v; __syncthreads();
  for (int o = 1; o < 256; o <<= 1){
    int xv = (t >= o) ? s[t-o] : 0;
    __syncthreads(); s[t] += xv; __syncthreads();
  }
  int excl = s[t] - v;
  bktBase[t] = excl;
  bktCur[t]  = excl;
  if (t == 0){ bktBase[256] = NE; off[NN] = NE; }
}

__global__ void k_part1(const int* __restrict__ ei, int* __restrict__ bktCur,
                        int* __restrict__ pairs){
  __shared__ int cnt[256]; __shared__ int base[256]; __shared__ int rank[256];
  int t = threadIdx.x;   // 1024 threads
  if (t < 256) cnt[t] = 0;
  __syncthreads();
  int tile = blockIdx.x*16384;
  #pragma unroll
  for (int k = 0; k < 16; ++k){
    int e = tile + k*1024 + t;
    if (e < NE) atomicAdd(&cnt[ei[NE+e]>>10], 1);
  }
  __syncthreads();
  if (t < 256){
    base[t] = cnt[t] ? atomicAdd(&bktCur[t], cnt[t]) : 0;
    rank[t] = 0;
  }
  __syncthreads();
  #pragma unroll
  for (int k = 0; k < 16; ++k){
    int e = tile + k*1024 + t;
    if (e < NE){
      int d = ei[NE+e], s = ei[e];
      int b = d >> 10;
      int r = atomicAdd(&rank[b], 1);
      pairs[base[b] + r] = (s<<10) | (d & 1023);
    }
  }
}

__global__ void k_part2(const int* __restrict__ pairs, const int* __restrict__ bktBase,
                        int* __restrict__ off, int* __restrict__ srcs){
  __shared__ int hist[1024]; __shared__ int cur[1024];
  int b = blockIdx.x, t = threadIdx.x;
  int p0 = bktBase[b], p1 = bktBase[b+1];
  int cntB = p1 - p0;
  int dstBase = b << 10;
  int width = min(1024, NN - dstBase);
  hist[t] = 0; __syncthreads();
  for (int i = t; i < cntB; i += 1024) atomicAdd(&hist[pairs[p0+i] & 1023], 1);
  __syncthreads();
  int h0 = hist[t];
  for (int o = 1; o < 1024; o <<= 1){
    int xv = (t >= o) ? hist[t-o] : 0;
    __syncthreads(); hist[t] += xv; __syncthreads();
  }
  int excl = hist[t] - h0;
  if (t < width) off[dstBase + t] = p0 + excl;
  cur[t] = excl; __syncthreads();
  for (int i = t; i < cntB; i += 1024){
    int v = pairs[p0+i];
    int r = atomicAdd(&cur[v & 1023], 1);
    srcs[p0 + r] = v >> 10;
  }
}

// ---------------- Block 1 (N=200000, C=16) ----------------
__global__ void k_agg1(const float4* __restrict__ feat, const int* __restrict__ srcs,
                       const int* __restrict__ off, const float* __restrict__ pos,
                       const float* __restrict__ w48, const float* __restrict__ bias,
                       float4* __restrict__ H4){
  int t = threadIdx.x;
  int eidx = t & 15;
  int d = blockIdx.x*16 + (t >> 4);
  int s0 = off[d], s1 = off[d+1];
  float NI = -__builtin_inff();
  float m[16];
  #pragma unroll
  for (int c = 0; c < 16; ++c) m[c] = NI;
  for (int j = s0 + eidx; j < s1; j += 16){
    float4 f = feat[srcs[j]];
    #pragma unroll
    for (int c = 0; c < 16; ++c)
      m[c] = fmaxf(m[c], f.x*w48[c] + f.y*w48[16+c] + f.z*w48[32+c]);
  }
  #pragma unroll
  for (int mask = 1; mask < 16; mask <<= 1){
    #pragma unroll
    for (int c = 0; c < 16; ++c) m[c] = fmaxf(m[c], __shfl_xor(m[c], mask, 64));
  }
  if (eidx == 0){
    float o[16];
    if (s1 > s0){
      float px = pos[3*d], py = pos[3*d+1];
      #pragma unroll
      for (int c = 0; c < 16; ++c) o[c] = m[c] + bias[c] - (px*w48[16+c] + py*w48[32+c]);
    } else {
      #pragma unroll
      for (int c = 0; c < 16; ++c) o[c] = 0.f;
    }
    H4[d*4+0] = make_float4(o[0],o[1],o[2],o[3]);
    H4[d*4+1] = make_float4(o[4],o[5],o[6],o[7]);
    H4[d*4+2] = make_float4(o[8],o[9],o[10],o[11]);
    H4[d*4+3] = make_float4(o[12],o[13],o[14],o[15]);
  }
}

__global__ void k_agg16w(const float4* __restrict__ A4, const int* __restrict__ srcs,
                         const int* __restrict__ off, const float* __restrict__ pos,
                         const float* __restrict__ wpos, const float* __restrict__ bias,
                         float4* __restrict__ H4){
  int t = threadIdx.x;
  int lane = t & 63;
  int d = blockIdx.x*4 + (t >> 6);
  int eidx = lane >> 2;
  int cg = lane & 3;
  int s0 = off[d], s1 = off[d+1];
  float NI = -__builtin_inff();
  float4 m = make_float4(NI, NI, NI, NI);
  for (int j = s0 + eidx; j < s1; j += 16){
    int s = srcs[j];
    float4 a = A4[s*4 + cg];
    m.x = fmaxf(m.x, a.x); m.y = fmaxf(m.y, a.y);
    m.z = fmaxf(m.z, a.z); m.w = fmaxf(m.w, a.w);
  }
  #pragma unroll
  for (int mask = 4; mask <= 32; mask <<= 1){
    m.x = fmaxf(m.x, __shfl_xor(m.x, mask, 64));
    m.y = fmaxf(m.y, __shfl_xor(m.y, mask, 64));
    m.z = fmaxf(m.z, __shfl_xor(m.z, mask, 64));
    m.w = fmaxf(m.w, __shfl_xor(m.w, mask, 64));
  }
  if (eidx == 0){
    float4 val = make_float4(0.f, 0.f, 0.f, 0.f);
    if (s1 > s0){
      float px = pos[3*d], py = pos[3*d+1];
      int c0 = cg*4;
      val.x = m.x + bias[c0+0] - (px*wpos[c0+0] + py*wpos[16+c0+0]);
      val.y = m.y + bias[c0+1] - (px*wpos[c0+1] + py*wpos[16+c0+1]);
      val.z = m.z + bias[c0+2] - (px*wpos[c0+2] + py*wpos[16+c0+2]);
      val.w = m.w + bias[c0+3] - (px*wpos[c0+3] + py*wpos[16+c0+3]);
    }
    H4[d*4 + cg] = val;
  }
}

__global__ void k_stats16(const float* __restrict__ H, float* __restrict__ st){
  int t = threadIdx.x;
  float s = 0.f, q = 0.f;
  for (int idx = blockIdx.x*256 + t; idx < NN*16; idx += gridDim.x*256){
    float v = H[idx]; s += v; q += v*v;
  }
  __shared__ float sv[256], sq[256];
  sv[t] = s; sq[t] = q; __syncthreads();
  for (int o = 128; o >= 16; o >>= 1){
    if (t < o){ sv[t]+=sv[t+o]; sq[t]+=sq[t+o]; } __syncthreads();
  }
  if (t < 16){ atomicAdd(&st[t], sv[t]); atomicAdd(&st[16+t], sq[t]); }
}

__global__ void k_prep2(const float* __restrict__ Hraw, const float* __restrict__ st1,
                        const float* __restrict__ pos, const float* __restrict__ w,
                        float4* __restrict__ A4){
  int idx = blockIdx.x*blockDim.x + threadIdx.x;
  if (idx >= NN*4) return;
  int i = idx >> 2, cg = idx & 3;
  const float inv_n = 1.f/(float)NN;
  float acc0 = 0.f, acc1 = 0.f, acc2 = 0.f, acc3 = 0.f;
  #pragma unroll
  for (int k = 0; k < 16; ++k){
    float mk = st1[k]*inv_n;
    float vk = st1[16+k]*inv_n - mk*mk;
    float ik = rsqrtf(vk + EPSV);
    float h = fmaxf((Hraw[i*16+k]-mk)*ik, 0.f);
    acc0 += h*w[k*16 + cg*4 + 0];
    acc1 += h*w[k*16 + cg*4 + 1];
    acc2 += h*w[k*16 + cg*4 + 2];
    acc3 += h*w[k*16 + cg*4 + 3];
  }
  float px = pos[3*i], py = pos[3*i+1];
  int c0 = cg*4;
  acc0 += px*w[256+c0+0] + py*w[272+c0+0];
  acc1 += px*w[256+c0+1] + py*w[272+c0+1];
  acc2 += px*w[256+c0+2] + py*w[272+c0+2];
  acc3 += px*w[256+c0+3] + py*w[272+c0+3];
  A4[idx] = make_float4(acc0, acc1, acc2, acc3);
}

__global__ void k_comb_pool(const float* __restrict__ H, const float* __restrict__ x,
                            const float* __restrict__ pos, const float* __restrict__ lw,
                            const float* __restrict__ st2, const float* __restrict__ xstats,
                            float* __restrict__ mem){
  int idx = blockIdx.x*blockDim.x + threadIdx.x;
  if (idx >= NN*4) return;
  int i = idx >> 2, cg = idx & 3;
  const float inv_n = 1.f/(float)NN;
  float mx = xstats[0]*inv_n, vx = xstats[1]*inv_n - mx*mx;
  float xc = x[i] - mx;
  float px = pos[3*i], py = pos[3*i+1];
  int cx = (int)(px * 80.f / 240.f); cx = min(max(cx,0),79);
  int cy = (int)(py * 60.f / 180.f); cy = min(max(cy,0),59);
  float* mrow = &mem[(cy*80+cx)*16 + cg*4];
  #pragma unroll
  for (int k = 0; k < 4; ++k){
    int c = cg*4 + k;
    float m2 = st2[c]*inv_n, v2 = st2[16+c]*inv_n - m2*m2;
    float i2 = rsqrtf(v2 + EPSV);
    float a = lw[c];
    float sc = a * rsqrtf(a*a*vx + EPSV);
    float v = (H[i*16+c]-m2)*i2 + xc*sc;
    v = fmaxf(v, 0.f);
    atomicAdd(&mrow[k], v);
  }
}

// ---------------- Fused tail: fence-free coherence + CONTENTION-FREE partial stats ----
__device__ __forceinline__ void stwt(float* p, float v){
  __hip_atomic_store(p, v, __ATOMIC_RELAXED, __HIP_MEMORY_SCOPE_AGENT);
}
__device__ __forceinline__ float ldwt(const float* p){
  return __hip_atomic_load(p, __ATOMIC_RELAXED, __HIP_MEMORY_SCOPE_AGENT);
}

__device__ __forceinline__ void gridbar(int* bar){
  __syncthreads();
  if (threadIdx.x == 0){
    __atomic_signal_fence(__ATOMIC_SEQ_CST);
    __builtin_amdgcn_s_waitcnt(0);
    __atomic_signal_fence(__ATOMIC_SEQ_CST);
    int g = __hip_atomic_load(bar+288, __ATOMIC_RELAXED, __HIP_MEMORY_SCOPE_AGENT);
    int slot = blockIdx.x & 7;
    int a = __hip_atomic_fetch_add(bar + slot*32, 1, __ATOMIC_RELAXED, __HIP_MEMORY_SCOPE_AGENT);
    bool released = false;
    if (a == (NWG/8 - 1)){
      int m = __hip_atomic_fetch_add(bar + 256, 1, __ATOMIC_RELAXED, __HIP_MEMORY_SCOPE_AGENT);
      if (m == 7){
        #pragma unroll
        for (int s = 0; s < 8; ++s)
          __hip_atomic_store(bar + s*32, 0, __ATOMIC_RELAXED, __HIP_MEMORY_SCOPE_AGENT);
        __hip_atomic_store(bar + 256, 0, __ATOMIC_RELAXED, __HIP_MEMORY_SCOPE_AGENT);
        __atomic_signal_fence(__ATOMIC_SEQ_CST);
        __builtin_amdgcn_s_waitcnt(0);
        __atomic_signal_fence(__ATOMIC_SEQ_CST);
        __hip_atomic_fetch_add(bar + 288, 1, __ATOMIC_RELAXED, __HIP_MEMORY_SCOPE_AGENT);
        released = true;
      }
    }
    if (!released){
      while (__hip_atomic_load(bar+288, __ATOMIC_RELAXED, __HIP_MEMORY_SCOPE_AGENT) == g)
        __builtin_amdgcn_s_sleep(2);
    }
  }
  __syncthreads();
}

// sum per-WG partial stats (NWG slots x twoC) into LDS out[0..twoC)
__device__ __forceinline__ void d_sumstats(const float* part, int twoC, float* out){
  int t = threadIdx.x;
  __syncthreads();
  if (t < twoC){
    float s = 0.f;
    for (int w = 0; w < NWG; ++w) s += ldwt(&part[w*twoC + t]);
    out[t] = s;
  }
  __syncthreads();
}

struct TailP {
  const float *mem1;
  const float *p1w,*p1b,*p2w,*p2b,*p3w,*p3b;
  const float *c1w2,*c1b2,*c2w2,*c2b2,*lw2,*lb2;
  const float *c1w3,*c1b3,*c2w3,*c2b3,*lw3,*lb3;
  const float *c1w4,*c1b4,*c2w4,*c2b4,*lw4,*lb4;
  float *g1,*S2,*SK2,*H2,*g2p;
  float *S3,*SK3,*H3,*g3p;
  float *S4,*SK4,*H4;
  float *P2sk,*P2c1,*P2c2,*P3sk,*P3c1,*P3c2,*P4sk,*P4c1,*P4c2;
  float *out;
  int *bar;
};

__device__ __forceinline__ void d_poollin(const float* mem, const float* W, const float* b,
                                          float* G, int n, int C, int gid, int gs){
  for (int idx = gid; idx < n*C; idx += gs){
    int i = idx / C, c = idx % C;
    float acc = b[c];
    for (int k = 0; k < C; ++k) acc += mem[i*C+k]*W[k*C+c];
    stwt(&G[idx], (acc > 1.f) ? acc : 0.f);
  }
}

__device__ __forceinline__ void d_gmm(const float* X, const float* W, const float* bias,
                                      float* S, int n, int K, int C,
                                      float* partOut, const float* instP,
                                      float* sv, float* sq, float* la, float* lb,
                                      int gid, int gs){
  const float inv_n = 1.f/(float)n;
  int t = threadIdx.x;
  if (instP){
    d_sumstats(instP, 2*K, sv);
    if (t < K){
      float mk = sv[t]*inv_n;
      float vk = sv[K+t]*inv_n - mk*mk;
      float ik = rsqrtf(vk + EPSV);
      la[t] = ik; lb[t] = -mk*ik;
    }
    __syncthreads();
  }
  float ls = 0.f, lq = 0.f;
  for (int idx = gid; idx < n*C; idx += gs){
    int i = idx / C, c = idx % C;
    float acc = bias ? bias[c] : 0.f;
    for (int k = 0; k < K; ++k){
      float xk = ldwt(&X[i*K+k]);
      if (instP) xk = fmaxf(fmaf(xk, la[k], lb[k]), 0.f);
      acc += xk*W[k*C+c];
    }
    stwt(&S[idx], acc);
    ls += acc; lq += acc*acc;
  }
  if (partOut){
    __syncthreads();
    sv[t] = ls; sq[t] = lq; __syncthreads();
    for (int o = 128; o >= C; o >>= 1){
      if (t < o){ sv[t]+=sv[t+o]; sq[t]+=sq[t+o]; } __syncthreads();
    }
    if (t < C){
      stwt(&partOut[blockIdx.x*2*C + t], sv[t]);
      stwt(&partOut[blockIdx.x*2*C + C + t], sq[t]);
    }
    __syncthreads();
  }
}

__device__ __forceinline__ void d_gridagg(const float* S, const float* wpos, const float* bias,
                                          float* H, float* partOut, int n, int gw, int gh, int C,
                                          float sx, float sy,
                                          float* sv, float* sq, int gid, int gs){
  float ls = 0.f, lq = 0.f;
  for (int idx = gid; idx < n*C; idx += gs){
    int i = idx / C, c = idx % C;
    int x = i % gw, y = i / gw;
    float wx = wpos[c], wy = wpos[C+c];
    float m = -__builtin_inff();
    for (int oy = -1; oy <= 1; ++oy){
      int ny = y + oy; if (ny < 0 || ny >= gh) continue;
      for (int ox = -1; ox <= 1; ++ox){
        int nx = x + ox; if (nx < 0 || nx >= gw) continue;
        float v = ldwt(&S[(ny*gw+nx)*C + c]) + (ox*sx)*wx + (oy*sy)*wy;
        m = fmaxf(m, v);
      }
    }
    float val = m + bias[c];
    stwt(&H[idx], val);
    ls += val; lq += val*val;
  }
  int t = threadIdx.x;
  __syncthreads();
  sv[t] = ls; sq[t] = lq; __syncthreads();
  for (int o = 128; o >= C; o >>= 1){
    if (t < o){ sv[t]+=sv[t+o]; sq[t]+=sq[t+o]; } __syncthreads();
  }
  if (t < C){
    stwt(&partOut[blockIdx.x*2*C + t], sv[t]);
    stwt(&partOut[blockIdx.x*2*C + C + t], sq[t]);
  }
  __syncthreads();
}

// Fused: gcombine(H,SK)->out + 2x2 pool + poollin -> Gp. One WG owns PC pooled cells.
__device__ __forceinline__ void d_pool_stage(const float* H, const float* SK,
                                             const float* P2, const float* Psk,
                                             const float* W, const float* b,
                                             float* outf, float* Gp,
                                             int gw, int gh, int C, int PC,
                                             float* lmem, float* sv, float* sq, int nwg){
  d_sumstats(P2, 2*C, sv);
  d_sumstats(Psk, 2*C, sq);
  int ow = gw >> 1;
  int ncell = ow*(gh>>1);
  int ntile = ncell / PC;
  int t = threadIdx.x;
  int cl = t / C;
  int c  = t % C;
  const float inv_n = 1.f/(float)(gw*gh);
  float m2 = sv[c]*inv_n, v2 = sv[C+c]*inv_n - m2*m2;
  float i2 = rsqrtf(v2 + EPSV);
  float ms = sq[c]*inv_n, vs = sq[C+c]*inv_n - ms*ms;
  float is_ = rsqrtf(vs + EPSV);
  for (int tile = blockIdx.x; tile < ntile; tile += nwg){
    int cell = tile*PC + cl;
    int px = cell % ow, py = cell / ow;
    float sum = 0.f;
    #pragma unroll
    for (int dy = 0; dy < 2; ++dy){
      #pragma unroll
      for (int dx = 0; dx < 2; ++dx){
        int gi = ((2*py+dy)*gw + (2*px+dx))*C + c;
        float v = (ldwt(&H[gi])-m2)*i2 + (ldwt(&SK[gi])-ms)*is_;
        v = fmaxf(v, 0.f);
        stwt(&outf[gi], v);
        sum += v;
      }
    }
    __syncthreads();
    lmem[cl*C + c] = sum;
    __syncthreads();
    float acc = b[c];
    for (int k = 0; k < C; ++k) acc += lmem[cl*C + k]*W[k*C+c];
    stwt(&Gp[cell*C + c], (acc > 1.f) ? acc : 0.f);
  }
}

__device__ __forceinline__ void d_gcombine(const float* H, const float* SK,
                                           const float* P2, const float* Psk,
                                           float* outf, int n, int C,
                                           float* sv, float* sq, int gid, int gs){
  d_sumstats(P2, 2*C, sv);
  d_sumstats(Psk, 2*C, sq);
  const float inv_n = 1.f/(float)n;
  int c0 = gid % C;   // gs % C == 0 -> constant per thread
  float m2 = sv[c0]*inv_n, v2 = sv[C+c0]*inv_n - m2*m2;
  float i2 = rsqrtf(v2 + EPSV);
  float ms = sq[c0]*inv_n, vs = sq[C+c0]*inv_n - ms*ms;
  float is_ = rsqrtf(vs + EPSV);
  for (int idx = gid; idx < n*C; idx += gs){
    float v = (ldwt(&H[idx])-m2)*i2 + (ldwt(&SK[idx])-ms)*is_;
    stwt(&outf[idx], fmaxf(v, 0.f));
  }
}

__global__ void __launch_bounds__(256) k_tail(TailP P){
  __shared__ float sv[256], sq[256], la[128], lb[128], lmem[256];
  const int gid = blockIdx.x*256 + threadIdx.x;
  const int gs  = NWG*256;
  int* bar = P.bar;

  d_poollin(P.mem1, P.p1w, P.p1b, P.g1, 4800, 16, gid, gs);
  gridbar(bar);
  // ---- block 2 (80x60, 16->32) ----
  d_gmm(P.g1, P.lw2, P.lb2, P.SK2, 4800, 16, 32, P.P2sk, nullptr, sv, sq, la, lb, gid, gs);
  d_gmm(P.g1, P.c1w2, nullptr, P.S2, 4800, 16, 32, nullptr, nullptr, sv, sq, la, lb, gid, gs);
  gridbar(bar);
  d_gridagg(P.S2, P.c1w2+16*32, P.c1b2, P.H2, P.P2c1, 4800, 80, 60, 32, 3.f, 3.f, sv, sq, gid, gs);
  gridbar(bar);
  d_gmm(P.H2, P.c2w2, nullptr, P.S2, 4800, 32, 32, nullptr, P.P2c1, sv, sq, la, lb, gid, gs);
  gridbar(bar);
  d_gridagg(P.S2, P.c2w2+32*32, P.c2b2, P.H2, P.P2c2, 4800, 80, 60, 32, 3.f, 3.f, sv, sq, gid, gs);
  gridbar(bar);
  d_pool_stage(P.H2, P.SK2, P.P2c2, P.P2sk, P.p2w, P.p2b, P.out, P.g2p, 80, 60, 32, 8, lmem, sv, sq, NWG);
  gridbar(bar);
  // ---- block 3 (40x30, 32->64) ----
  d_gmm(P.g2p, P.lw3, P.lb3, P.SK3, 1200, 32, 64, P.P3sk, nullptr, sv, sq, la, lb, gid, gs);
  d_gmm(P.g2p, P.c1w3, nullptr, P.S3, 1200, 32, 64, nullptr, nullptr, sv, sq, la, lb, gid, gs);
  gridbar(bar);
  d_gridagg(P.S3, P.c1w3+32*64, P.c1b3, P.H3, P.P3c1, 1200, 40, 30, 64, 6.f, 6.f, sv, sq, gid, gs);
  gridbar(bar);
  d_gmm(P.H3, P.c2w3, nullptr, P.S3, 1200, 64, 64, nullptr, P.P3c1, sv, sq, la, lb, gid, gs);
  gridbar(bar);
  d_gridagg(P.S3, P.c2w3+64*64, P.c2b3, P.H3, P.P3c2, 1200, 40, 30, 64, 6.f, 6.f, sv, sq, gid, gs);
  gridbar(bar);
  d_pool_stage(P.H3, P.SK3, P.P3c2, P.P3sk, P.p3w, P.p3b, P.out+153600, P.g3p, 40, 30, 64, 4, lmem, sv, sq, NWG);
  gridbar(bar);
  // ---- block 4 (20x15, 64->128) ----
  d_gmm(P.g3p, P.lw4, P.lb4, P.SK4, 300, 64, 128, P.P4sk, nullptr, sv, sq, la, lb, gid, gs);
  d_gmm(P.g3p, P.c1w4, nullptr, P.S4, 300, 64, 128, nullptr, nullptr, sv, sq, la, lb, gid, gs);
  gridbar(bar);
  d_gridagg(P.S4, P.c1w4+64*128, P.c1b4, P.H4, P.P4c1, 300, 20, 15, 128, 12.f, 12.f, sv, sq, gid, gs);
  gridbar(bar);
  d_gmm(P.H4, P.c2w4, nullptr, P.S4, 300, 128, 128, nullptr, P.P4c1, sv, sq, la, lb, gid, gs);
  gridbar(bar);
  d_gridagg(P.S4, P.c2w4+128*128, P.c2b4, P.H4, P.P4c2, 300, 20, 15, 128, 12.f, 12.f, sv, sq, gid, gs);
  gridbar(bar);
  d_gcombine(P.H4, P.SK4, P.P4c2, P.P4sk, P.out+230400, 300, 128, sv, sq, gid, gs);
}

extern "C" void kernel_launch(void* const* d_in, const int* in_sizes, int n_in,
                              void* d_out, int out_size, void* d_ws, size_t ws_size,
                              hipStream_t stream){
  const float* x   = (const float*)d_in[0];
  const float* pos = (const float*)d_in[1];
  const int*   ei  = (const int*)d_in[2];
  const float* b1_c1w = (const float*)d_in[3];
  const float* b1_c1b = (const float*)d_in[4];
  const float* b1_c2w = (const float*)d_in[5];
  const float* b1_c2b = (const float*)d_in[6];
  const float* b1_lw  = (const float*)d_in[7];
  const float* b2_c1w = (const float*)d_in[9];
  const float* b2_c1b = (const float*)d_in[10];
  const float* b2_c2w = (const float*)d_in[11];
  const float* b2_c2b = (const float*)d_in[12];
  const float* b2_lw  = (const float*)d_in[13];
  const float* b2_lb  = (const float*)d_in[14];
  const float* b3_c1w = (const float*)d_in[15];
  const float* b3_c1b = (const float*)d_in[16];
  const float* b3_c2w = (const float*)d_in[17];
  const float* b3_c2b = (const float*)d_in[18];
  const float* b3_lw  = (const float*)d_in[19];
  const float* b3_lb  = (const float*)d_in[20];
  const float* b4_c1w = (const float*)d_in[21];
  const float* b4_c1b = (const float*)d_in[22];
  const float* b4_c2w = (const float*)d_in[23];
  const float* b4_c2b = (const float*)d_in[24];
  const float* b4_lw  = (const float*)d_in[25];
  const float* b4_lb  = (const float*)d_in[26];
  const float* p1w = (const float*)d_in[27];
  const float* p1b = (const float*)d_in[28];
  const float* p2w = (const float*)d_in[29];
  const float* p2b = (const float*)d_in[30];
  const float* p3w = (const float*)d_in[31];
  const float* p3b = (const float*)d_in[32];
  float* out = (float*)d_out;

  // ---- workspace carve ----
  float4* feat = (float4*)d_ws;       // NN float4 (3.2MB)
  float* A  = (float*)(feat + NN);    // NN*16 fp32; pairs aliases (dead before A written)
  int* pairs = (int*)A;               // NE ints — ALIAS
  float* H  = A + NN*16;              // NN*16
  // Z region (single memset): bktCnt..bktCur, bar, block-1 stats, mem1
  int* bktCnt  = (int*)(H + NN*16);   // 256
  int* bktBase = bktCnt + 256;        // 257
  int* bktCur  = bktBase + 257;       // 256  (ends at 769)
  int* bar     = bktCnt + 784;        // 320  (ends at 1104)
  float* STz   = (float*)(bktCnt + 1104);
  float* xstats = STz;                // 2
  float* st1    = STz + 16;           // 32
  float* st2    = STz + 64;           // 32 (pad to 128)
  float* mem1   = STz + 128;          // 76800
  const size_t ZBYTES = (size_t)(1104 + 128 + 76800) * 4;
  float* g1   = mem1 + 76800;
  float* b2S  = g1 + 76800;           // 4800*32
  float* b2SK = b2S + 153600;
  float* b2H  = b2SK + 153600;
  float* g2p  = b2H + 153600;         // 1200*32
  float* b3S  = g2p + 38400;          // 1200*64
  float* b3SK = b3S + 76800;
  float* b3H  = b3SK + 76800;
  float* g3p  = b3H + 76800;          // 300*64
  float* b4S  = g3p + 19200;          // 300*128
  float* b4SK = b4S + 38400;
  float* b4H  = b4SK + 38400;
  // per-WG partial stats (always fully written each launch; no memset needed)
  float* P2sk = b4H + 38400;          // 120*64
  float* P2c1 = P2sk + 7680;
  float* P2c2 = P2c1 + 7680;
  float* P3sk = P2c2 + 7680;          // 120*128
  float* P3c1 = P3sk + 15360;
  float* P3c2 = P3c1 + 15360;
  float* P4sk = P3c2 + 15360;         // 120*256
  float* P4c1 = P4sk + 30720;
  float* P4c2 = P4c1 + 30720;
  int* off    = (int*)(P4c2 + 30720); // NN+1
  int* srcs   = off + (NN+1);         // NE

  hipMemsetAsync(bktCnt, 0, ZBYTES, stream);

  const int B = 256;
  // CSR build (fused with feat/xstats prep)
  k_cnt_prep<<<(NE+4095)/4096, 256, 0, stream>>>(ei, bktCnt, x, pos, feat, xstats);
  k_bktscan <<<1, 256, 0, stream>>>(bktCnt, bktBase, bktCur, off);
  k_part1   <<<(NE+16383)/16384, 1024, 0, stream>>>(ei, bktCur, pairs);
  k_part2   <<<196, 1024, 0, stream>>>(pairs, bktBase, off, srcs);

  // Block 1
  k_agg1    <<<NN/16, B, 0, stream>>>(feat, srcs, off, pos, b1_c1w, b1_c1b, (float4*)H);
  k_stats16 <<<256, B, 0, stream>>>(H, st1);
  k_prep2   <<<(NN*4+B-1)/B, B, 0, stream>>>(H, st1, pos, b1_c2w, (float4*)A);
  k_agg16w  <<<NN/4, B, 0, stream>>>((const float4*)A, srcs, off, pos, b1_c2w+256, b1_c2b, (float4*)H);
  k_stats16 <<<256, B, 0, stream>>>(H, st2);
  k_comb_pool<<<(NN*4+B-1)/B, B, 0, stream>>>(H, x, pos, b1_lw, st2, xstats, mem1);

  // Fused tail (contention-free partial stats + fence-free barrier)
  TailP P;
  P.mem1 = mem1;
  P.p1w = p1w; P.p1b = p1b; P.p2w = p2w; P.p2b = p2b; P.p3w = p3w; P.p3b = p3b;
  P.c1w2 = b2_c1w; P.c1b2 = b2_c1b; P.c2w2 = b2_c2w; P.c2b2 = b2_c2b; P.lw2 = b2_lw; P.lb2 = b2_lb;
  P.c1w3 = b3_c1w; P.c1b3 = b3_c1b; P.c2w3 = b3_c2w; P.c2b3 = b3_c2b; P.lw3 = b3_lw; P.lb3 = b3_lb;
  P.c1w4 = b4_c1w; P.c1b4 = b4_c1b; P.c2w4 = b4_c2w; P.c2b4 = b4_c2b; P.lw4 = b4_lw; P.lb4 = b4_lb;
  P.g1 = g1; P.S2 = b2S; P.SK2 = b2SK; P.H2 = b2H; P.g2p = g2p;
  P.S3 = b3S; P.SK3 = b3SK; P.H3 = b3H; P.g3p = g3p;
  P.S4 = b4S; P.SK4 = b4SK; P.H4 = b4H;
  P.P2sk = P2sk; P.P2c1 = P2c1; P.P2c2 = P2c2;
  P.P3sk = P3sk; P.P3c1 = P3c1; P.P3c2 = P3c2;
  P.P4sk = P4sk; P.P4c1 = P4c1; P.P4c2 = P4c2;
  P.out = out; P.bar = bar;
  k_tail<<<NWG, 256, 0, stream>>>(P);
}

// Round 12
// 676.264 us; speedup vs baseline: 1.7032x; 1.0149x over previous
//
#include <hip/hip_runtime.h>

#define NN 200000
#define NE 3200000
#define NWG 120
static constexpr float EPSV = 1e-5f;

// ---------------- CSR build: 2-level bucket sort ----------------
__global__ void k_cnt_prep(const int* __restrict__ ei, int* __restrict__ bktCnt,
                           const float* __restrict__ x, const float* __restrict__ pos,
                           float4* __restrict__ feat, float* __restrict__ xstats){
  __shared__ int cnt[256];
  __shared__ float sv[256], sq[256];
  int t = threadIdx.x;
  cnt[t] = 0;
  int i = blockIdx.x*256 + t;
  float xf = 0.f;
  if (i < NN){
    xf = x[i];
    feat[i] = make_float4(xf, pos[3*i], pos[3*i+1], 0.f);
  }
  sv[t] = (i < NN) ? xf : 0.f;
  sq[t] = sv[t]*sv[t];
  __syncthreads();
  int tile = blockIdx.x*4096;
  #pragma unroll
  for (int k = 0; k < 16; ++k){
    int e = tile + k*256 + t;
    if (e < NE) atomicAdd(&cnt[ei[NE+e]>>10], 1);
  }
  for (int o = 128; o > 0; o >>= 1){
    __syncthreads();
    if (t < o){ sv[t]+=sv[t+o]; sq[t]+=sq[t+o]; }
  }
  __syncthreads();
  if (t == 0){ atomicAdd(&xstats[0], sv[0]); atomicAdd(&xstats[1], sq[0]); }
  if (cnt[t]) atomicAdd(&bktCnt[t], cnt[t]);
}

__global__ void k_bktscan(const int* __restrict__ bktCnt, int* __restrict__ bktBase,
                          int* __restrict__ bktCur, int* __restrict__ off){
  __shared__ int s[256];
  int t = threadIdx.x;
  int v = bktCnt[t];
  s[t] = v; __syncthreads();
  for (int o = 1; o < 256; o <<= 1){
    int xv = (t >= o) ? s[t-o] : 0;
    __syncthreads(); s[t] += xv; __syncthreads();
  }
  int excl = s[t] - v;
  bktBase[t] = excl;
  bktCur[t]  = excl;
  if (t == 0){ bktBase[256] = NE; off[NN] = NE; }
}

__global__ void k_part1(const int* __restrict__ ei, int* __restrict__ bktCur,
                        int* __restrict__ pairs){
  __shared__ int cnt[256]; __shared__ int base[256]; __shared__ int rank[256];
  int t = threadIdx.x;   // 1024 threads
  if (t < 256) cnt[t] = 0;
  __syncthreads();
  int tile = blockIdx.x*16384;
  #pragma unroll
  for (int k = 0; k < 16; ++k){
    int e = tile + k*1024 + t;
    if (e < NE) atomicAdd(&cnt[ei[NE+e]>>10], 1);
  }
  __syncthreads();
  if (t < 256){
    base[t] = cnt[t] ? atomicAdd(&bktCur[t], cnt[t]) : 0;
    rank[t] = 0;
  }
  __syncthreads();
  #pragma unroll
  for (int k = 0; k < 16; ++k){
    int e = tile + k*1024 + t;
    if (e < NE){
      int d = ei[NE+e], s = ei[e];
      int b = d >> 10;
      int r = atomicAdd(&rank[b], 1);
      pairs[base[b] + r] = (s<<10) | (d & 1023);
    }
  }
}

__global__ void k_part2(const int* __restrict__ pairs, const int* __restrict__ bktBase,
                        int* __restrict__ off, int* __restrict__ srcs){
  __shared__ int hist[1024]; __shared__ int cur[1024];
  int b = blockIdx.x, t = threadIdx.x;
  int p0 = bktBase[b], p1 = bktBase[b+1];
  int cntB = p1 - p0;
  int dstBase = b << 10;
  int width = min(1024, NN - dstBase);
  hist[t] = 0; __syncthreads();
  for (int i = t; i < cntB; i += 1024) atomicAdd(&hist[pairs[p0+i] & 1023], 1);
  __syncthreads();
  int h0 = hist[t];
  for (int o = 1; o < 1024; o <<= 1){
    int xv = (t >= o) ? hist[t-o] : 0;
    __syncthreads(); hist[t] += xv; __syncthreads();
  }
  int excl = hist[t] - h0;
  if (t < width) off[dstBase + t] = p0 + excl;
  cur[t] = excl; __syncthreads();
  for (int i = t; i < cntB; i += 1024){
    int v = pairs[p0+i];
    int r = atomicAdd(&cur[v & 1023], 1);
    srcs[p0 + r] = v >> 10;
  }
}

// ---------------- Block 1 (N=200000, C=16) ----------------
__global__ void k_agg1(const float4* __restrict__ feat, const int* __restrict__ srcs,
                       const int* __restrict__ off, const float* __restrict__ pos,
                       const float* __restrict__ w48, const float* __restrict__ bias,
                       float4* __restrict__ H4){
  int t = threadIdx.x;
  int eidx = t & 15;
  int d = blockIdx.x*16 + (t >> 4);
  int s0 = off[d], s1 = off[d+1];
  float NI = -__builtin_inff();
  float m[16];
  #pragma unroll
  for (int c = 0; c < 16; ++c) m[c] = NI;
  for (int j = s0 + eidx; j < s1; j += 16){
    float4 f = feat[srcs[j]];
    #pragma unroll
    for (int c = 0; c < 16; ++c)
      m[c] = fmaxf(m[c], f.x*w48[c] + f.y*w48[16+c] + f.z*w48[32+c]);
  }
  #pragma unroll
  for (int mask = 1; mask < 16; mask <<= 1){
    #pragma unroll
    for (int c = 0; c < 16; ++c) m[c] = fmaxf(m[c], __shfl_xor(m[c], mask, 64));
  }
  if (eidx == 0){
    float o[16];
    if (s1 > s0){
      float px = pos[3*d], py = pos[3*d+1];
      #pragma unroll
      for (int c = 0; c < 16; ++c) o[c] = m[c] + bias[c] - (px*w48[16+c] + py*w48[32+c]);
    } else {
      #pragma unroll
      for (int c = 0; c < 16; ++c) o[c] = 0.f;
    }
    H4[d*4+0] = make_float4(o[0],o[1],o[2],o[3]);
    H4[d*4+1] = make_float4(o[4],o[5],o[6],o[7]);
    H4[d*4+2] = make_float4(o[8],o[9],o[10],o[11]);
    H4[d*4+3] = make_float4(o[12],o[13],o[14],o[15]);
  }
}

__global__ void k_agg16w(const float4* __restrict__ A4, const int* __restrict__ srcs,
                         const int* __restrict__ off, const float* __restrict__ pos,
                         const float* __restrict__ wpos, const float* __restrict__ bias,
                         float4* __restrict__ H4){
  int t = threadIdx.x;
  int lane = t & 63;
  int d = blockIdx.x*4 + (t >> 6);
  int eidx = lane >> 2;
  int cg = lane & 3;
  int s0 = off[d], s1 = off[d+1];
  float NI = -__builtin_inff();
  float4 m = make_float4(NI, NI, NI, NI);
  for (int j = s0 + eidx; j < s1; j += 16){
    int s = srcs[j];
    float4 a = A4[s*4 + cg];
    m.x = fmaxf(m.x, a.x); m.y = fmaxf(m.y, a.y);
    m.z = fmaxf(m.z, a.z); m.w = fmaxf(m.w, a.w);
  }
  #pragma unroll
  for (int mask = 4; mask <= 32; mask <<= 1){
    m.x = fmaxf(m.x, __shfl_xor(m.x, mask, 64));
    m.y = fmaxf(m.y, __shfl_xor(m.y, mask, 64));
    m.z = fmaxf(m.z, __shfl_xor(m.z, mask, 64));
    m.w = fmaxf(m.w, __shfl_xor(m.w, mask, 64));
  }
  if (eidx == 0){
    float4 val = make_float4(0.f, 0.f, 0.f, 0.f);
    if (s1 > s0){
      float px = pos[3*d], py = pos[3*d+1];
      int c0 = cg*4;
      val.x = m.x + bias[c0+0] - (px*wpos[c0+0] + py*wpos[16+c0+0]);
      val.y = m.y + bias[c0+1] - (px*wpos[c0+1] + py*wpos[16+c0+1]);
      val.z = m.z + bias[c0+2] - (px*wpos[c0+2] + py*wpos[16+c0+2]);
      val.w = m.w + bias[c0+3] - (px*wpos[c0+3] + py*wpos[16+c0+3]);
    }
    H4[d*4 + cg] = val;
  }
}

__global__ void k_stats16(const float* __restrict__ H, float* __restrict__ st){
  int t = threadIdx.x;
  float s = 0.f, q = 0.f;
  for (int idx = blockIdx.x*256 + t; idx < NN*16; idx += gridDim.x*256){
    float v = H[idx]; s += v; q += v*v;
  }
  __shared__ float sv[256], sq[256];
  sv[t] = s; sq[t] = q; __syncthreads();
  for (int o = 128; o >= 16; o >>= 1){
    if (t < o){ sv[t]+=sv[t+o]; sq[t]+=sq[t+o]; } __syncthreads();
  }
  if (t < 16){ atomicAdd(&st[t], sv[t]); atomicAdd(&st[16+t], sq[t]); }
}

__global__ void k_prep2(const float* __restrict__ Hraw, const float* __restrict__ st1,
                        const float* __restrict__ pos, const float* __restrict__ w,
                        float4* __restrict__ A4){
  int idx = blockIdx.x*blockDim.x + threadIdx.x;
  if (idx >= NN*4) return;
  int i = idx >> 2, cg = idx & 3;
  const float inv_n = 1.f/(float)NN;
  float acc0 = 0.f, acc1 = 0.f, acc2 = 0.f, acc3 = 0.f;
  #pragma unroll
  for (int k = 0; k < 16; ++k){
    float mk = st1[k]*inv_n;
    float vk = st1[16+k]*inv_n - mk*mk;
    float ik = rsqrtf(vk + EPSV);
    float h = fmaxf((Hraw[i*16+k]-mk)*ik, 0.f);
    acc0 += h*w[k*16 + cg*4 + 0];
    acc1 += h*w[k*16 + cg*4 + 1];
    acc2 += h*w[k*16 + cg*4 + 2];
    acc3 += h*w[k*16 + cg*4 + 3];
  }
  float px = pos[3*i], py = pos[3*i+1];
  int c0 = cg*4;
  acc0 += px*w[256+c0+0] + py*w[272+c0+0];
  acc1 += px*w[256+c0+1] + py*w[272+c0+1];
  acc2 += px*w[256+c0+2] + py*w[272+c0+2];
  acc3 += px*w[256+c0+3] + py*w[272+c0+3];
  A4[idx] = make_float4(acc0, acc1, acc2, acc3);
}

__global__ void k_comb_pool(const float* __restrict__ H, const float* __restrict__ x,
                            const float* __restrict__ pos, const float* __restrict__ lw,
                            const float* __restrict__ st2, const float* __restrict__ xstats,
                            float* __restrict__ mem){
  int idx = blockIdx.x*blockDim.x + threadIdx.x;
  if (idx >= NN*4) return;
  int i = idx >> 2, cg = idx & 3;
  const float inv_n = 1.f/(float)NN;
  float mx = xstats[0]*inv_n, vx = xstats[1]*inv_n - mx*mx;
  float xc = x[i] - mx;
  float px = pos[3*i], py = pos[3*i+1];
  int cx = (int)(px * 80.f / 240.f); cx = min(max(cx,0),79);
  int cy = (int)(py * 60.f / 180.f); cy = min(max(cy,0),59);
  float* mrow = &mem[(cy*80+cx)*16 + cg*4];
  #pragma unroll
  for (int k = 0; k < 4; ++k){
    int c = cg*4 + k;
    float m2 = st2[c]*inv_n, v2 = st2[16+c]*inv_n - m2*m2;
    float i2 = rsqrtf(v2 + EPSV);
    float a = lw[c];
    float sc = a * rsqrtf(a*a*vx + EPSV);
    float v = (H[i*16+c]-m2)*i2 + xc*sc;
    v = fmaxf(v, 0.f);
    atomicAdd(&mrow[k], v);
  }
}

// ---------------- Fused tail: fence-free coherence + flag-array barrier ----------------
__device__ __forceinline__ void stwt(float* p, float v){
  __hip_atomic_store(p, v, __ATOMIC_RELAXED, __HIP_MEMORY_SCOPE_AGENT);
}
__device__ __forceinline__ float ldwt(const float* p){
  return __hip_atomic_load(p, __ATOMIC_RELAXED, __HIP_MEMORY_SCOPE_AGENT);
}
__device__ __forceinline__ void stwti(int* p, int v){
  __hip_atomic_store(p, v, __ATOMIC_RELAXED, __HIP_MEMORY_SCOPE_AGENT);
}
__device__ __forceinline__ int ldwti(const int* p){
  return __hip_atomic_load(p, __ATOMIC_RELAXED, __HIP_MEMORY_SCOPE_AGENT);
}

// Flag-array barrier: arrival = ONE write-through store (no RMW serialization);
// detection = 120 parallel flag loads + __syncthreads_and. Monotone gens, no reset.
__device__ __forceinline__ void gridbar(int* flags, int gen){
  __syncthreads();
  if (threadIdx.x == 0){
    __atomic_signal_fence(__ATOMIC_SEQ_CST);
    __builtin_amdgcn_s_waitcnt(0);   // my stores durable at coherent point
    __atomic_signal_fence(__ATOMIC_SEQ_CST);
    stwti(&flags[blockIdx.x], gen);
  }
  int ok;
  do {
    int mine = 1;
    if (threadIdx.x < NWG) mine = (ldwti(&flags[threadIdx.x]) >= gen) ? 1 : 0;
    ok = __syncthreads_and(mine);
    if (!ok) __builtin_amdgcn_s_sleep(1);
  } while (!ok);
}

struct TailP {
  const float *mem1;
  const float *p1w,*p1b,*p2w,*p2b,*p3w,*p3b;
  const float *c1w2,*c1b2,*c2w2,*c2b2,*lw2,*lb2;
  const float *c1w3,*c1b3,*c2w3,*c2b3,*lw3,*lb3;
  const float *c1w4,*c1b4,*c2w4,*c2b4,*lw4,*lb4;
  float *g1,*S2,*SK2,*H2,*g2p;
  float *S3,*SK3,*H3,*g3p;
  float *S4,*SK4,*H4;
  float *stB2sk,*stB2c1,*stB2c2,*stB3sk,*stB3c1,*stB3c2,*stB4sk,*stB4c1,*stB4c2;
  float *out;
  int *flags;
};

__device__ __forceinline__ void d_poollin(const float* mem, const float* W, const float* b,
                                          float* G, int n, int C, int gid, int gs){
  for (int idx = gid; idx < n*C; idx += gs){
    int i = idx / C, c = idx % C;
    float acc = b[c];
    for (int k = 0; k < C; ++k) acc += mem[i*C+k]*W[k*C+c];
    stwt(&G[idx], (acc > 1.f) ? acc : 0.f);
  }
}

__device__ __forceinline__ void d_gmm(const float* X, const float* W, const float* bias,
                                      float* S, int n, int K, int C,
                                      float* st, const float* instats,
                                      float* sv, float* sq, float* la, float* lb,
                                      int gid, int gs){
  const float inv_n = 1.f/(float)n;
  int t = threadIdx.x;
  if (instats){
    __syncthreads();
    if (t < K){
      float mk = ldwt(&instats[t])*inv_n;
      float vk = ldwt(&instats[K+t])*inv_n - mk*mk;
      float ik = rsqrtf(vk + EPSV);
      la[t] = ik; lb[t] = -mk*ik;
    }
    __syncthreads();
  }
  float ls = 0.f, lq = 0.f;
  for (int idx = gid; idx < n*C; idx += gs){
    int i = idx / C, c = idx % C;
    float acc = bias ? bias[c] : 0.f;
    for (int k = 0; k < K; ++k){
      float xk = ldwt(&X[i*K+k]);
      if (instats) xk = fmaxf(fmaf(xk, la[k], lb[k]), 0.f);
      acc += xk*W[k*C+c];
    }
    stwt(&S[idx], acc);
    ls += acc; lq += acc*acc;
  }
  if (st){
    __syncthreads();
    sv[t] = ls; sq[t] = lq; __syncthreads();
    for (int o = 128; o >= C; o >>= 1){
      if (t < o){ sv[t]+=sv[t+o]; sq[t]+=sq[t+o]; } __syncthreads();
    }
    if (t < C){ atomicAdd(&st[t], sv[t]); atomicAdd(&st[C+t], sq[t]); }
    __syncthreads();
  }
}

__device__ __forceinline__ void d_gridagg(const float* S, const float* wpos, const float* bias,
                                          float* H, float* st, int n, int gw, int gh, int C,
                                          float sx, float sy,
                                          float* sv, float* sq, int gid, int gs){
  float ls = 0.f, lq = 0.f;
  for (int idx = gid; idx < n*C; idx += gs){
    int i = idx / C, c = idx % C;
    int x = i % gw, y = i / gw;
    float wx = wpos[c], wy = wpos[C+c];
    float m = -__builtin_inff();
    for (int oy = -1; oy <= 1; ++oy){
      int ny = y + oy; if (ny < 0 || ny >= gh) continue;
      for (int ox = -1; ox <= 1; ++ox){
        int nx = x + ox; if (nx < 0 || nx >= gw) continue;
        float v = ldwt(&S[(ny*gw+nx)*C + c]) + (ox*sx)*wx + (oy*sy)*wy;
        m = fmaxf(m, v);
      }
    }
    float val = m + bias[c];
    stwt(&H[idx], val);
    ls += val; lq += val*val;
  }
  int t = threadIdx.x;
  __syncthreads();
  sv[t] = ls; sq[t] = lq; __syncthreads();
  for (int o = 128; o >= C; o >>= 1){
    if (t < o){ sv[t]+=sv[t+o]; sq[t]+=sq[t+o]; } __syncthreads();
  }
  if (t < C){ atomicAdd(&st[t], sv[t]); atomicAdd(&st[C+t], sq[t]); }
  __syncthreads();
}

// Fused: gcombine(H,SK)->out + 2x2 pool + poollin -> Gp. One WG owns PC pooled cells.
__device__ __forceinline__ void d_pool_stage(const float* H, const float* SK,
                                             const float* st2, const float* stsk,
                                             const float* W, const float* b,
                                             float* outf, float* Gp,
                                             int gw, int gh, int C, int PC,
                                             float* lmem, int nwg){
  int ow = gw >> 1;
  int ncell = ow*(gh>>1);
  int ntile = ncell / PC;
  int t = threadIdx.x;
  int cl = t / C;
  int c  = t % C;
  const float inv_n = 1.f/(float)(gw*gh);
  float m2 = ldwt(&st2[c])*inv_n, v2 = ldwt(&st2[C+c])*inv_n - m2*m2;
  float i2 = rsqrtf(v2 + EPSV);
  float ms = ldwt(&stsk[c])*inv_n, vs = ldwt(&stsk[C+c])*inv_n - ms*ms;
  float is_ = rsqrtf(vs + EPSV);
  for (int tile = blockIdx.x; tile < ntile; tile += nwg){
    int cell = tile*PC + cl;
    int px = cell % ow, py = cell / ow;
    float sum = 0.f;
    #pragma unroll
    for (int dy = 0; dy < 2; ++dy){
      #pragma unroll
      for (int dx = 0; dx < 2; ++dx){
        int gi = ((2*py+dy)*gw + (2*px+dx))*C + c;
        float v = (ldwt(&H[gi])-m2)*i2 + (ldwt(&SK[gi])-ms)*is_;
        v = fmaxf(v, 0.f);
        stwt(&outf[gi], v);
        sum += v;
      }
    }
    __syncthreads();
    lmem[cl*C + c] = sum;
    __syncthreads();
    float acc = b[c];
    for (int k = 0; k < C; ++k) acc += lmem[cl*C + k]*W[k*C+c];
    stwt(&Gp[cell*C + c], (acc > 1.f) ? acc : 0.f);
  }
}

__device__ __forceinline__ void d_gcombine(const float* H, const float* SK,
                                           const float* st2, const float* stsk,
                                           float* outf, int n, int C, int gid, int gs){
  const float inv_n = 1.f/(float)n;
  for (int idx = gid; idx < n*C; idx += gs){
    int c = idx % C;
    float m2 = ldwt(&st2[c])*inv_n, v2 = ldwt(&st2[C+c])*inv_n - m2*m2;
    float i2 = rsqrtf(v2 + EPSV);
    float ms = ldwt(&stsk[c])*inv_n, vs = ldwt(&stsk[C+c])*inv_n - ms*ms;
    float is_ = rsqrtf(vs + EPSV);
    float v = (ldwt(&H[idx])-m2)*i2 + (ldwt(&SK[idx])-ms)*is_;
    stwt(&outf[idx], fmaxf(v, 0.f));
  }
}

__global__ void __launch_bounds__(256) k_tail(TailP P){
  __shared__ float sv[256], sq[256], la[128], lb[128], lmem[256];
  const int gid = blockIdx.x*256 + threadIdx.x;
  const int gs  = NWG*256;
  int* flags = P.flags;
  int gen = 0;

  d_poollin(P.mem1, P.p1w, P.p1b, P.g1, 4800, 16, gid, gs);
  gridbar(flags, ++gen);
  // ---- block 2 (80x60, 16->32) ----
  d_gmm(P.g1, P.lw2, P.lb2, P.SK2, 4800, 16, 32, P.stB2sk, nullptr, sv, sq, la, lb, gid, gs);
  d_gmm(P.g1, P.c1w2, nullptr, P.S2, 4800, 16, 32, nullptr, nullptr, sv, sq, la, lb, gid, gs);
  gridbar(flags, ++gen);
  d_gridagg(P.S2, P.c1w2+16*32, P.c1b2, P.H2, P.stB2c1, 4800, 80, 60, 32, 3.f, 3.f, sv, sq, gid, gs);
  gridbar(flags, ++gen);
  d_gmm(P.H2, P.c2w2, nullptr, P.S2, 4800, 32, 32, nullptr, P.stB2c1, sv, sq, la, lb, gid, gs);
  gridbar(flags, ++gen);
  d_gridagg(P.S2, P.c2w2+32*32, P.c2b2, P.H2, P.stB2c2, 4800, 80, 60, 32, 3.f, 3.f, sv, sq, gid, gs);
  gridbar(flags, ++gen);
  d_pool_stage(P.H2, P.SK2, P.stB2c2, P.stB2sk, P.p2w, P.p2b, P.out, P.g2p, 80, 60, 32, 8, lmem, NWG);
  gridbar(flags, ++gen);
  // ---- block 3 (40x30, 32->64) ----
  d_gmm(P.g2p, P.lw3, P.lb3, P.SK3, 1200, 32, 64, P.stB3sk, nullptr, sv, sq, la, lb, gid, gs);
  d_gmm(P.g2p, P.c1w3, nullptr, P.S3, 1200, 32, 64, nullptr, nullptr, sv, sq, la, lb, gid, gs);
  gridbar(flags, ++gen);
  d_gridagg(P.S3, P.c1w3+32*64, P.c1b3, P.H3, P.stB3c1, 1200, 40, 30, 64, 6.f, 6.f, sv, sq, gid, gs);
  gridbar(flags, ++gen);
  d_gmm(P.H3, P.c2w3, nullptr, P.S3, 1200, 64, 64, nullptr, P.stB3c1, sv, sq, la, lb, gid, gs);
  gridbar(flags, ++gen);
  d_gridagg(P.S3, P.c2w3+64*64, P.c2b3, P.H3, P.stB3c2, 1200, 40, 30, 64, 6.f, 6.f, sv, sq, gid, gs);
  gridbar(flags, ++gen);
  d_pool_stage(P.H3, P.SK3, P.stB3c2, P.stB3sk, P.p3w, P.p3b, P.out+153600, P.g3p, 40, 30, 64, 4, lmem, NWG);
  gridbar(flags, ++gen);
  // ---- block 4 (20x15, 64->128) ----
  d_gmm(P.g3p, P.lw4, P.lb4, P.SK4, 300, 64, 128, P.stB4sk, nullptr, sv, sq, la, lb, gid, gs);
  d_gmm(P.g3p, P.c1w4, nullptr, P.S4, 300, 64, 128, nullptr, nullptr, sv, sq, la, lb, gid, gs);
  gridbar(flags, ++gen);
  d_gridagg(P.S4, P.c1w4+64*128, P.c1b4, P.H4, P.stB4c1, 300, 20, 15, 128, 12.f, 12.f, sv, sq, gid, gs);
  gridbar(flags, ++gen);
  d_gmm(P.H4, P.c2w4, nullptr, P.S4, 300, 128, 128, nullptr, P.stB4c1, sv, sq, la, lb, gid, gs);
  gridbar(flags, ++gen);
  d_gridagg(P.S4, P.c2w4+128*128, P.c2b4, P.H4, P.stB4c2, 300, 20, 15, 128, 12.f, 12.f, sv, sq, gid, gs);
  gridbar(flags, ++gen);
  d_gcombine(P.H4, P.SK4, P.stB4c2, P.stB4sk, P.out+230400, 300, 128, gid, gs);
}

extern "C" void kernel_launch(void* const* d_in, const int* in_sizes, int n_in,
                              void* d_out, int out_size, void* d_ws, size_t ws_size,
                              hipStream_t stream){
  const float* x   = (const float*)d_in[0];
  const float* pos = (const float*)d_in[1];
  const int*   ei  = (const int*)d_in[2];
  const float* b1_c1w = (const float*)d_in[3];
  const float* b1_c1b = (const float*)d_in[4];
  const float* b1_c2w = (const float*)d_in[5];
  const float* b1_c2b = (const float*)d_in[6];
  const float* b1_lw  = (const float*)d_in[7];
  const float* b2_c1w = (const float*)d_in[9];
  const float* b2_c1b = (const float*)d_in[10];
  const float* b2_c2w = (const float*)d_in[11];
  const float* b2_c2b = (const float*)d_in[12];
  const float* b2_lw  = (const float*)d_in[13];
  const float* b2_lb  = (const float*)d_in[14];
  const float* b3_c1w = (const float*)d_in[15];
  const float* b3_c1b = (const float*)d_in[16];
  const float* b3_c2w = (const float*)d_in[17];
  const float* b3_c2b = (const float*)d_in[18];
  const float* b3_lw  = (const float*)d_in[19];
  const float* b3_lb  = (const float*)d_in[20];
  const float* b4_c1w = (const float*)d_in[21];
  const float* b4_c1b = (const float*)d_in[22];
  const float* b4_c2w = (const float*)d_in[23];
  const float* b4_c2b = (const float*)d_in[24];
  const float* b4_lw  = (const float*)d_in[25];
  const float* b4_lb  = (const float*)d_in[26];
  const float* p1w = (const float*)d_in[27];
  const float* p1b = (const float*)d_in[28];
  const float* p2w = (const float*)d_in[29];
  const float* p2b = (const float*)d_in[30];
  const float* p3w = (const float*)d_in[31];
  const float* p3b = (const float*)d_in[32];
  float* out = (float*)d_out;

  // ---- workspace carve ----
  float4* feat = (float4*)d_ws;       // NN float4 (3.2MB)
  float* A  = (float*)(feat + NN);    // NN*16 fp32; pairs aliases (dead before A written)
  int* pairs = (int*)A;               // NE ints — ALIAS
  float* H  = A + NN*16;              // NN*16
  // Z region (single memset): bucket counters, flags, stats, mem1
  int* bktCnt  = (int*)(H + NN*16);   // 256
  int* bktBase = bktCnt + 256;        // 257
  int* bktCur  = bktBase + 257;       // 256  (ends at 769)
  int* flags   = bktCnt + 784;        // 128  (ends at 912; pad to 1024)
  float* STz   = (float*)(bktCnt + 1024);
  float* xstats = STz;                // 2
  float* st1    = STz + 16;
  float* st2    = STz + 64;
  float* stB2sk = STz + 128;
  float* stB2c1 = STz + 192;
  float* stB2c2 = STz + 256;
  float* stB3sk = STz + 320;
  float* stB3c1 = STz + 448;
  float* stB3c2 = STz + 576;
  float* stB4sk = STz + 704;
  float* stB4c1 = STz + 960;
  float* stB4c2 = STz + 1216;         // ..1471, pad to 1536
  float* mem1   = STz + 1536;         // 76800
  const size_t ZBYTES = (size_t)(1024 + 1536 + 76800) * 4;
  float* g1   = mem1 + 76800;
  float* b2S  = g1 + 76800;           // 4800*32
  float* b2SK = b2S + 153600;
  float* b2H  = b2SK + 153600;
  float* g2p  = b2H + 153600;         // 1200*32
  float* b3S  = g2p + 38400;          // 1200*64
  float* b3SK = b3S + 76800;
  float* b3H  = b3SK + 76800;
  float* g3p  = b3H + 76800;          // 300*64
  float* b4S  = g3p + 19200;          // 300*128
  float* b4SK = b4S + 38400;
  float* b4H  = b4SK + 38400;
  int* off    = (int*)(b4H + 38400);  // NN+1
  int* srcs   = off + (NN+1);         // NE

  hipMemsetAsync(bktCnt, 0, ZBYTES, stream);

  const int B = 256;
  // CSR build (fused with feat/xstats prep)
  k_cnt_prep<<<(NE+4095)/4096, 256, 0, stream>>>(ei, bktCnt, x, pos, feat, xstats);
  k_bktscan <<<1, 256, 0, stream>>>(bktCnt, bktBase, bktCur, off);
  k_part1   <<<(NE+16383)/16384, 1024, 0, stream>>>(ei, bktCur, pairs);
  k_part2   <<<196, 1024, 0, stream>>>(pairs, bktBase, off, srcs);

  // Block 1
  k_agg1    <<<NN/16, B, 0, stream>>>(feat, srcs, off, pos, b1_c1w, b1_c1b, (float4*)H);
  k_stats16 <<<256, B, 0, stream>>>(H, st1);
  k_prep2   <<<(NN*4+B-1)/B, B, 0, stream>>>(H, st1, pos, b1_c2w, (float4*)A);
  k_agg16w  <<<NN/4, B, 0, stream>>>((const float4*)A, srcs, off, pos, b1_c2w+256, b1_c2b, (float4*)H);
  k_stats16 <<<256, B, 0, stream>>>(H, st2);
  k_comb_pool<<<(NN*4+B-1)/B, B, 0, stream>>>(H, x, pos, b1_lw, st2, xstats, mem1);

  // Fused tail (atomic stats + flag-array barrier)
  TailP P;
  P.mem1 = mem1;
  P.p1w = p1w; P.p1b = p1b; P.p2w = p2w; P.p2b = p2b; P.p3w = p3w; P.p3b = p3b;
  P.c1w2 = b2_c1w; P.c1b2 = b2_c1b; P.c2w2 = b2_c2w; P.c2b2 = b2_c2b; P.lw2 = b2_lw; P.lb2 = b2_lb;
  P.c1w3 = b3_c1w; P.c1b3 = b3_c1b; P.c2w3 = b3_c2w; P.c2b3 = b3_c2b; P.lw3 = b3_lw; P.lb3 = b3_lb;
  P.c1w4 = b4_c1w; P.c1b4 = b4_c1b; P.c2w4 = b4_c2w; P.c2b4 = b4_c2b; P.lw4 = b4_lw; P.lb4 = b4_lb;
  P.g1 = g1; P.S2 = b2S; P.SK2 = b2SK; P.H2 = b2H; P.g2p = g2p;
  P.S3 = b3S; P.SK3 = b3SK; P.H3 = b3H; P.g3p = g3p;
  P.S4 = b4S; P.SK4 = b4SK; P.H4 = b4H;
  P.stB2sk = stB2sk; P.stB2c1 = stB2c1; P.stB2c2 = stB2c2;
  P.stB3sk = stB3sk; P.stB3c1 = stB3c1; P.stB3c2 = stB3c2;
  P.stB4sk = stB4sk; P.stB4c1 = stB4c1; P.stB4c2 = stB4c2;
  P.out = out; P.flags = flags;
  k_tail<<<NWG, 256, 0, stream>>>(P);
}